// Round 1
// baseline (5187.343 us; speedup 1.0000x reference)
//
#include <hip/hip_runtime.h>
#include <math.h>

// ---------------- problem constants ----------------
constexpr int SEQ   = 2048;   // L
constexpr int HID   = 2048;
constexpr int NHQ   = 16;
constexpr int NHKV  = 4;
constexpr int GQ    = NHQ / NHKV;   // 4
constexpr int DH    = 128;
constexpr int CKS   = 32;     // compress window
constexpr int CKST  = 16;     // compress stride
constexpr int NCMP  = (SEQ - CKS) / CKST + 1;  // 127
constexpr int BSZ   = 64;     // selection block
constexpr int NTOP  = 16;
constexpr int NBLK  = SEQ / BSZ;   // 32
constexpr int MBB   = BSZ / CKST;  // 4
constexpr int WINW  = 512;
constexpr float SCALE = 0.08838834764831845f;  // 1/sqrt(128)

// ---------------- generic tiled fp32 GEMM: C[M,N] = A[M,K] @ B[K,N] ----------------
// M,N multiples of 64; K multiple of 16.
__global__ __launch_bounds__(256) void gemm_f32(const float* __restrict__ A,
                                                const float* __restrict__ B,
                                                float* __restrict__ C,
                                                int M, int N, int K) {
  __shared__ float As[16][68];
  __shared__ float Bs[16][68];
  const int t = threadIdx.x;
  const int tx = t & 15, ty = t >> 4;
  const int row0 = blockIdx.y * 64, col0 = blockIdx.x * 64;
  const int lar = t >> 2;          // 0..63
  const int lac = (t & 3) << 2;    // 0,4,8,12
  const int lbr = t >> 4;          // 0..15
  const int lbc = (t & 15) << 2;   // 0..60
  float acc[4][4] = {};
  for (int k0 = 0; k0 < K; k0 += 16) {
    float4 av = *(const float4*)(A + (size_t)(row0 + lar) * K + k0 + lac);
    float4 bv = *(const float4*)(B + (size_t)(k0 + lbr) * N + col0 + lbc);
    As[lac + 0][lar] = av.x;
    As[lac + 1][lar] = av.y;
    As[lac + 2][lar] = av.z;
    As[lac + 3][lar] = av.w;
    *(float4*)(&Bs[lbr][lbc]) = bv;
    __syncthreads();
#pragma unroll
    for (int kk = 0; kk < 16; ++kk) {
      float4 a4 = *(const float4*)(&As[kk][ty << 2]);
      float4 b4 = *(const float4*)(&Bs[kk][tx << 2]);
      float am[4] = {a4.x, a4.y, a4.z, a4.w};
      float bm[4] = {b4.x, b4.y, b4.z, b4.w};
#pragma unroll
      for (int mi = 0; mi < 4; ++mi)
#pragma unroll
        for (int ni = 0; ni < 4; ++ni)
          acc[mi][ni] += am[mi] * bm[ni];
    }
    __syncthreads();
  }
#pragma unroll
  for (int mi = 0; mi < 4; ++mi) {
    float4 o = {acc[mi][0], acc[mi][1], acc[mi][2], acc[mi][3]};
    *(float4*)(C + (size_t)(row0 + (ty << 2) + mi) * N + col0 + (tx << 2)) = o;
  }
}

// ---------------- gate = sigmoid(x @ Wg), Wg is (HID,3) ----------------
__global__ __launch_bounds__(128) void gate_kernel(const float* __restrict__ x,
                                                   const float* __restrict__ Wg,
                                                   float* __restrict__ gate) {
  const int i = blockIdx.x;
  const int t = threadIdx.x;
  float a0 = 0.f, a1 = 0.f, a2 = 0.f;
  for (int k = t; k < HID; k += 128) {
    float xv = x[(size_t)i * HID + k];
    a0 += xv * Wg[k * 3 + 0];
    a1 += xv * Wg[k * 3 + 1];
    a2 += xv * Wg[k * 3 + 2];
  }
  __shared__ float r0[128], r1[128], r2[128];
  r0[t] = a0; r1[t] = a1; r2[t] = a2;
  __syncthreads();
  for (int s = 64; s > 0; s >>= 1) {
    if (t < s) { r0[t] += r0[t + s]; r1[t] += r1[t + s]; r2[t] += r2[t + s]; }
    __syncthreads();
  }
  if (t == 0) {
    gate[i * 3 + 0] = 1.f / (1.f + expf(-r0[0]));
    gate[i * 3 + 1] = 1.f / (1.f + expf(-r1[0]));
    gate[i * 3 + 2] = 1.f / (1.f + expf(-r2[0]));
  }
}

// ---------------- compression: ck[n,h,:]=(win_k+pe)@Wck[h], cv[n,h,:]=win_v@Wcv[h] ----------------
__global__ __launch_bounds__(128) void compress_kernel(const float* __restrict__ k,
                                                       const float* __restrict__ v,
                                                       const float* __restrict__ Wck,
                                                       const float* __restrict__ Wcv,
                                                       const float* __restrict__ pe,
                                                       float* __restrict__ ck,
                                                       float* __restrict__ cv) {
  const int n = blockIdx.x / NHKV;
  const int h = blockIdx.x % NHKV;
  const int t = threadIdx.x;  // output dim
  __shared__ float wk[CKS * DH];
  __shared__ float wv[CKS * DH];
  for (int e = t; e < CKS * DH; e += 128) {
    int s = e >> 7, dd = e & 127;
    size_t src = ((size_t)(n * CKST + s) * NHKV + h) * DH + dd;
    wk[e] = k[src] + pe[((size_t)h * CKS + s) * DH + dd];
    wv[e] = v[src];
  }
  __syncthreads();
  float ak0 = 0.f, ak1 = 0.f, av0 = 0.f, av1 = 0.f;
  const float* wckp = Wck + (size_t)h * CKS * DH * DH + t;
  const float* wcvp = Wcv + (size_t)h * CKS * DH * DH + t;
#pragma unroll 4
  for (int e = 0; e < CKS * DH; e += 2) {
    ak0 += wk[e] * wckp[(size_t)e * DH];
    av0 += wv[e] * wcvp[(size_t)e * DH];
    ak1 += wk[e + 1] * wckp[(size_t)(e + 1) * DH];
    av1 += wv[e + 1] * wcvp[(size_t)(e + 1) * DH];
  }
  ck[((size_t)n * NHKV + h) * DH + t] = ak0 + ak1;
  cv[((size_t)n * NHKV + h) * DH + t] = av0 + av1;
}

// ---------------- RoPE: rows flattened as (row, head); pos = row * posmul ----------------
__global__ __launch_bounds__(64) void rope_kernel(const float* in, float* out,
                                                  int heads, int posmul) {
  const int rh = blockIdx.x;
  const int r = rh / heads;
  const int t = threadIdx.x;  // 0..63
  const float* p = in + (size_t)rh * DH;
  float x1 = p[t], x2 = p[t + 64];
  float inv = powf(10000.f, -(float)t / 64.f);
  float ang = (float)(r * posmul) * inv;
  float c, s;
  sincosf(ang, &s, &c);
  out[(size_t)rh * DH + t]      = x1 * c - x2 * s;
  out[(size_t)rh * DH + t + 64] = x2 * c + x1 * s;
}

// ---------------- compressed attention + block top-k selection (one block per query i) ------------
__global__ __launch_bounds__(128) void cmp_attn_kernel(const float* __restrict__ q,
                                                       const float* __restrict__ ck,
                                                       const float* __restrict__ cv,
                                                       float* __restrict__ cmp_out,
                                                       int* __restrict__ selblk) {
  const int i = blockIdx.x;
  const int t = threadIdx.x;
  __shared__ float qs[DH];
  __shared__ float pbuf[128];
  __shared__ float red[128];
  __shared__ float pscore[NHKV][132];  // index up to b*4+4 = 128; zero padded
  __shared__ float blks[NBLK];
  for (int h = 0; h < NHKV; ++h) {
    pscore[h][t] = 0.f;
    if (t < 4) pscore[h][128 + t] = 0.f;
  }
  int jmax = (i >= CKS - 1) ? ((i - (CKS - 1)) / CKST) : -1;
  if (jmax > NCMP - 1) jmax = NCMP - 1;
  __syncthreads();
  for (int h = 0; h < NHKV; ++h) {
    for (int g = 0; g < GQ; ++g) {
      const int hq = h * GQ + g;
      qs[t] = q[((size_t)i * NHQ + hq) * DH + t];
      __syncthreads();
      const bool valid = (t <= jmax);
      float val = -INFINITY;
      if (valid) {
        const float4* ckp = (const float4*)(ck + ((size_t)t * NHKV + h) * DH);
        float a0 = 0.f, a1 = 0.f;
#pragma unroll
        for (int d4 = 0; d4 < DH / 8; ++d4) {
          float4 k0 = ckp[2 * d4], k1 = ckp[2 * d4 + 1];
          a0 += qs[d4 * 8 + 0] * k0.x + qs[d4 * 8 + 1] * k0.y + qs[d4 * 8 + 2] * k0.z + qs[d4 * 8 + 3] * k0.w;
          a1 += qs[d4 * 8 + 4] * k1.x + qs[d4 * 8 + 5] * k1.y + qs[d4 * 8 + 6] * k1.z + qs[d4 * 8 + 7] * k1.w;
        }
        val = (a0 + a1) * SCALE;
      }
      red[t] = valid ? val : -INFINITY;
      __syncthreads();
      for (int s = 64; s > 0; s >>= 1) { if (t < s) red[t] = fmaxf(red[t], red[t + s]); __syncthreads(); }
      const float m = red[0];
      __syncthreads();
      const float e = valid ? expf(val - m) : 0.f;
      red[t] = e;
      __syncthreads();
      for (int s = 64; s > 0; s >>= 1) { if (t < s) red[t] += red[t + s]; __syncthreads(); }
      const float denom = fmaxf(red[0], 1e-20f);
      __syncthreads();
      const float p = e / denom;
      pbuf[t] = p;
      pscore[h][t] += p;
      __syncthreads();
      float acc0 = 0.f, acc1 = 0.f;
      const int nj = jmax + 1;
      for (int j = 0; j + 1 < nj; j += 2) {
        acc0 += pbuf[j] * cv[((size_t)j * NHKV + h) * DH + t];
        acc1 += pbuf[j + 1] * cv[((size_t)(j + 1) * NHKV + h) * DH + t];
      }
      if (nj & 1) acc0 += pbuf[nj - 1] * cv[((size_t)(nj - 1) * NHKV + h) * DH + t];
      cmp_out[((size_t)i * NHQ + hq) * DH + t] = acc0 + acc1;
      __syncthreads();
    }
  }
  // block scores + top-16 per kv head
  const int qblk = i / BSZ;
  for (int h = 0; h < NHKV; ++h) {
    if (t < NBLK) {
      const float offw[5] = {1.f, 2.f, 2.f, 2.f, 1.f};
      float s = 0.f;
#pragma unroll
      for (int o = 0; o < 5; ++o) s += pscore[h][t * MBB + o] * offw[o];
      const bool causal = (t <= qblk);
      const bool forced = (t < 1) || ((t > qblk - 2) && causal);
      blks[t] = causal ? (forced ? INFINITY : s) : -INFINITY;
    }
    __syncthreads();
    if (t == 0) {
      float tmp[NBLK];
      for (int b = 0; b < NBLK; ++b) tmp[b] = blks[b];
      for (int s = 0; s < NTOP; ++s) {
        int best = -1;
        float bv = -INFINITY;
        for (int b = 0; b < NBLK; ++b)
          if (tmp[b] > bv) { bv = tmp[b]; best = b; }   // strict > == lowest-index tie-break
        selblk[((size_t)i * NHKV + h) * NTOP + s] = best;
        if (best >= 0) tmp[best] = -INFINITY;
      }
    }
    __syncthreads();
  }
}

// ---------------- selected + window attention + gated combine (one block per (i,hq)) --------------
__global__ __launch_bounds__(128) void sel_win_kernel(const float* __restrict__ q,
                                                      const float* __restrict__ kr,
                                                      const float* __restrict__ v,
                                                      const int* __restrict__ selblk,
                                                      const float* __restrict__ gate,
                                                      const float* __restrict__ cmp_out,
                                                      float* __restrict__ outc) {
  const int bid = blockIdx.x;
  const int i = bid / NHQ;
  const int hq = bid % NHQ;
  const int h = hq >> 2;
  const int t = threadIdx.x;
  __shared__ float qs[DH];
  __shared__ float sl[NTOP * BSZ];  // 1024
  __shared__ float red[128];
  __shared__ int sb[NTOP];
  qs[t] = q[((size_t)i * NHQ + hq) * DH + t];
  if (t < NTOP) sb[t] = selblk[((size_t)i * NHKV + h) * NTOP + t];
  __syncthreads();

  // ---- selected branch ----
  float lmax = -INFINITY;
#pragma unroll
  for (int rep = 0; rep < NTOP * BSZ / 128; ++rep) {
    const int u = rep * 128 + t;
    const int s = u >> 6, c = u & 63;
    const int b = sb[s];
    const int j = b * BSZ + c;
    float val = -INFINITY;
    if (b >= 0 && j <= i) {
      const float4* kp = (const float4*)(kr + ((size_t)j * NHKV + h) * DH);
      float a0 = 0.f, a1 = 0.f;
#pragma unroll
      for (int d4 = 0; d4 < DH / 8; ++d4) {
        float4 k0 = kp[2 * d4], k1 = kp[2 * d4 + 1];
        a0 += qs[d4 * 8 + 0] * k0.x + qs[d4 * 8 + 1] * k0.y + qs[d4 * 8 + 2] * k0.z + qs[d4 * 8 + 3] * k0.w;
        a1 += qs[d4 * 8 + 4] * k1.x + qs[d4 * 8 + 5] * k1.y + qs[d4 * 8 + 6] * k1.z + qs[d4 * 8 + 7] * k1.w;
      }
      val = (a0 + a1) * SCALE;
    }
    sl[u] = val;
    lmax = fmaxf(lmax, val);
  }
  red[t] = lmax;
  __syncthreads();
  for (int s = 64; s > 0; s >>= 1) { if (t < s) red[t] = fmaxf(red[t], red[t + s]); __syncthreads(); }
  const float m1 = red[0];
  __syncthreads();
  float lsum = 0.f;
#pragma unroll
  for (int rep = 0; rep < NTOP * BSZ / 128; ++rep) {
    const int u = rep * 128 + t;
    const float vv = sl[u];
    const float e = (vv == -INFINITY) ? 0.f : expf(vv - m1);
    sl[u] = e;
    lsum += e;
  }
  red[t] = lsum;
  __syncthreads();
  for (int s = 64; s > 0; s >>= 1) { if (t < s) red[t] += red[t + s]; __syncthreads(); }
  const float S1 = red[0];
  __syncthreads();
  float acc1a = 0.f, acc1b = 0.f;
  for (int s = 0; s < NTOP; ++s) {
    const int b = sb[s];
    if (b < 0) continue;  // uniform branch
    const float* vp = v + (((size_t)b * BSZ) * NHKV + h) * DH + t;
#pragma unroll 4
    for (int c = 0; c < BSZ; c += 2) {
      acc1a += sl[(s << 6) + c] * vp[(size_t)c * NHKV * DH];
      acc1b += sl[(s << 6) + c + 1] * vp[(size_t)(c + 1) * NHKV * DH];
    }
  }
  const float spv = (acc1a + acc1b) / S1;
  __syncthreads();  // done reading sl

  // ---- window branch ----
  const int j0 = (i > WINW) ? i - WINW : 0;
  const int nw = i - j0 + 1;  // <= 513
  float wmax = -INFINITY;
  for (int u = t; u < nw; u += 128) {
    const int j = j0 + u;
    const float4* kp = (const float4*)(kr + ((size_t)j * NHKV + h) * DH);
    float a0 = 0.f, a1 = 0.f;
#pragma unroll
    for (int d4 = 0; d4 < DH / 8; ++d4) {
      float4 k0 = kp[2 * d4], k1 = kp[2 * d4 + 1];
      a0 += qs[d4 * 8 + 0] * k0.x + qs[d4 * 8 + 1] * k0.y + qs[d4 * 8 + 2] * k0.z + qs[d4 * 8 + 3] * k0.w;
      a1 += qs[d4 * 8 + 4] * k1.x + qs[d4 * 8 + 5] * k1.y + qs[d4 * 8 + 6] * k1.z + qs[d4 * 8 + 7] * k1.w;
    }
    const float val = (a0 + a1) * SCALE;
    sl[u] = val;
    wmax = fmaxf(wmax, val);
  }
  red[t] = wmax;
  __syncthreads();
  for (int s = 64; s > 0; s >>= 1) { if (t < s) red[t] = fmaxf(red[t], red[t + s]); __syncthreads(); }
  const float m2 = red[0];
  __syncthreads();
  float wsum = 0.f;
  for (int u = t; u < nw; u += 128) {
    const float e = expf(sl[u] - m2);
    sl[u] = e;
    wsum += e;
  }
  red[t] = wsum;
  __syncthreads();
  for (int s = 64; s > 0; s >>= 1) { if (t < s) red[t] += red[t + s]; __syncthreads(); }
  const float S2 = red[0];
  __syncthreads();
  float acc2a = 0.f, acc2b = 0.f;
  for (int u = 0; u + 1 < nw; u += 2) {
    acc2a += sl[u] * v[(((size_t)(j0 + u)) * NHKV + h) * DH + t];
    acc2b += sl[u + 1] * v[(((size_t)(j0 + u + 1)) * NHKV + h) * DH + t];
  }
  if (nw & 1) acc2a += sl[nw - 1] * v[(((size_t)(j0 + nw - 1)) * NHKV + h) * DH + t];
  const float swv = (acc2a + acc2b) / S2;

  // ---- gated combine ----
  const float g0 = gate[i * 3 + 0], g1 = gate[i * 3 + 1], g2 = gate[i * 3 + 2];
  const size_t o = ((size_t)i * NHQ + hq) * DH + t;
  outc[o] = g0 * cmp_out[o] + g1 * spv + g2 * swv;
}

// ---------------- launcher ----------------
extern "C" void kernel_launch(void* const* d_in, const int* in_sizes, int n_in,
                              void* d_out, int out_size, void* d_ws, size_t ws_size,
                              hipStream_t stream) {
  const float* x   = (const float*)d_in[0];
  // d_in[1] = cu_seqlens (single sequence; unused)
  const float* Wq  = (const float*)d_in[2];
  const float* Wk  = (const float*)d_in[3];
  const float* Wv  = (const float*)d_in[4];
  const float* Wo  = (const float*)d_in[5];
  const float* Wck = (const float*)d_in[6];
  const float* Wcv = (const float*)d_in[7];
  const float* pe  = (const float*)d_in[8];
  const float* Wg  = (const float*)d_in[9];
  float* out = (float*)d_out;

  float* ws = (float*)d_ws;
  float* q      = ws;                                   // SEQ*NHQ*DH   = 4194304
  float* kbuf   = q    + (size_t)SEQ * NHQ * DH;        // SEQ*NHKV*DH  = 1048576
  float* vbuf   = kbuf + (size_t)SEQ * NHKV * DH;
  float* kr     = vbuf + (size_t)SEQ * NHKV * DH;
  float* ck     = kr   + (size_t)SEQ * NHKV * DH;       // NCMP*NHKV*DH = 65024
  float* cv     = ck   + (size_t)NCMP * NHKV * DH;
  float* gbuf   = cv   + (size_t)NCMP * NHKV * DH;      // SEQ*3 (pad 4)
  float* cmpo   = gbuf + (size_t)SEQ * 4;               // SEQ*NHQ*DH
  int*   selblk = (int*)(cmpo + (size_t)SEQ * NHQ * DH);// SEQ*NHKV*NTOP ints
  float* comb   = q;  // alias: each (i,hq) row of q is read only by the block that rewrites it

  // projections
  gemm_f32<<<dim3(NHQ * DH / 64, SEQ / 64), 256, 0, stream>>>(x, Wq, q, SEQ, NHQ * DH, HID);
  gemm_f32<<<dim3(NHKV * DH / 64, SEQ / 64), 256, 0, stream>>>(x, Wk, kbuf, SEQ, NHKV * DH, HID);
  gemm_f32<<<dim3(NHKV * DH / 64, SEQ / 64), 256, 0, stream>>>(x, Wv, vbuf, SEQ, NHKV * DH, HID);
  gate_kernel<<<SEQ, 128, 0, stream>>>(x, Wg, gbuf);
  // compression (uses pre-RoPE k, v)
  compress_kernel<<<NCMP * NHKV, 128, 0, stream>>>(kbuf, vbuf, Wck, Wcv, pe, ck, cv);
  // RoPE
  rope_kernel<<<SEQ * NHQ, 64, 0, stream>>>(q, q, NHQ, 1);
  rope_kernel<<<SEQ * NHKV, 64, 0, stream>>>(kbuf, kr, NHKV, 1);
  rope_kernel<<<NCMP * NHKV, 64, 0, stream>>>(ck, ck, NHKV, CKST);
  // compressed attention + top-k block selection
  cmp_attn_kernel<<<SEQ, 128, 0, stream>>>(q, ck, cv, cmpo, selblk);
  // selected + window attention + gated combine
  sel_win_kernel<<<SEQ * NHQ, 128, 0, stream>>>(q, kr, vbuf, selblk, gbuf, cmpo, comb);
  // output projection
  gemm_f32<<<dim3(HID / 64, SEQ / 64), 256, 0, stream>>>(comb, Wo, out, SEQ, HID, NHQ * DH);
}

// Round 2
// 1562.177 us; speedup vs baseline: 3.3206x; 3.3206x over previous
//
#include <hip/hip_runtime.h>
#include <math.h>

// ---------------- problem constants ----------------
constexpr int SEQ   = 2048;   // L
constexpr int HID   = 2048;
constexpr int NHQ   = 16;
constexpr int NHKV  = 4;
constexpr int GQ    = NHQ / NHKV;   // 4
constexpr int DH    = 128;
constexpr int CKS   = 32;     // compress window
constexpr int CKST  = 16;     // compress stride
constexpr int NCMP  = (SEQ - CKS) / CKST + 1;  // 127
constexpr int BSZ   = 64;     // selection block
constexpr int NTOP  = 16;
constexpr int NBLK  = SEQ / BSZ;   // 32
constexpr int MBB   = BSZ / CKST;  // 4
constexpr int WINW  = 512;
constexpr float SCALE = 0.08838834764831845f;  // 1/sqrt(128)

typedef __attribute__((ext_vector_type(8))) short short8;     // 8 bf16 (4 VGPRs)
typedef __attribute__((ext_vector_type(4))) float f32x4;
typedef __attribute__((ext_vector_type(4))) unsigned short us4;

static __device__ __forceinline__ unsigned short f2bf(float f) {
  unsigned u = __builtin_bit_cast(unsigned, f);
  u = (u + 0x7fffu + ((u >> 16) & 1u)) >> 16;
  return (unsigned short)u;
}

// ---------------- generic tiled fp32 GEMM: C[M,N] = A[M,K] @ B[K,N] ----------------
__global__ __launch_bounds__(256) void gemm_f32(const float* __restrict__ A,
                                                const float* __restrict__ B,
                                                float* __restrict__ C,
                                                int M, int N, int K) {
  __shared__ float As[16][68];
  __shared__ float Bs[16][68];
  const int t = threadIdx.x;
  const int tx = t & 15, ty = t >> 4;
  const int row0 = blockIdx.y * 64, col0 = blockIdx.x * 64;
  const int lar = t >> 2;
  const int lac = (t & 3) << 2;
  const int lbr = t >> 4;
  const int lbc = (t & 15) << 2;
  float acc[4][4] = {};
  for (int k0 = 0; k0 < K; k0 += 16) {
    float4 av = *(const float4*)(A + (size_t)(row0 + lar) * K + k0 + lac);
    float4 bv = *(const float4*)(B + (size_t)(k0 + lbr) * N + col0 + lbc);
    As[lac + 0][lar] = av.x;
    As[lac + 1][lar] = av.y;
    As[lac + 2][lar] = av.z;
    As[lac + 3][lar] = av.w;
    *(float4*)(&Bs[lbr][lbc]) = bv;
    __syncthreads();
#pragma unroll
    for (int kk = 0; kk < 16; ++kk) {
      float4 a4 = *(const float4*)(&As[kk][ty << 2]);
      float4 b4 = *(const float4*)(&Bs[kk][tx << 2]);
      float am[4] = {a4.x, a4.y, a4.z, a4.w};
      float bm[4] = {b4.x, b4.y, b4.z, b4.w};
#pragma unroll
      for (int mi = 0; mi < 4; ++mi)
#pragma unroll
        for (int ni = 0; ni < 4; ++ni)
          acc[mi][ni] += am[mi] * bm[ni];
    }
    __syncthreads();
  }
#pragma unroll
  for (int mi = 0; mi < 4; ++mi) {
    float4 o = {acc[mi][0], acc[mi][1], acc[mi][2], acc[mi][3]};
    *(float4*)(C + (size_t)(row0 + (ty << 2) + mi) * N + col0 + (tx << 2)) = o;
  }
}

// ---------------- gate = sigmoid(x @ Wg) ----------------
__global__ __launch_bounds__(128) void gate_kernel(const float* __restrict__ x,
                                                   const float* __restrict__ Wg,
                                                   float* __restrict__ gate) {
  const int i = blockIdx.x;
  const int t = threadIdx.x;
  float a0 = 0.f, a1 = 0.f, a2 = 0.f;
  for (int k = t; k < HID; k += 128) {
    float xv = x[(size_t)i * HID + k];
    a0 += xv * Wg[k * 3 + 0];
    a1 += xv * Wg[k * 3 + 1];
    a2 += xv * Wg[k * 3 + 2];
  }
  __shared__ float r0[128], r1[128], r2[128];
  r0[t] = a0; r1[t] = a1; r2[t] = a2;
  __syncthreads();
  for (int s = 64; s > 0; s >>= 1) {
    if (t < s) { r0[t] += r0[t + s]; r1[t] += r1[t + s]; r2[t] += r2[t + s]; }
    __syncthreads();
  }
  if (t == 0) {
    gate[i * 3 + 0] = 1.f / (1.f + expf(-r0[0]));
    gate[i * 3 + 1] = 1.f / (1.f + expf(-r1[0]));
    gate[i * 3 + 2] = 1.f / (1.f + expf(-r2[0]));
  }
}

// ---------------- compression ----------------
__global__ __launch_bounds__(128) void compress_kernel(const float* __restrict__ k,
                                                       const float* __restrict__ v,
                                                       const float* __restrict__ Wck,
                                                       const float* __restrict__ Wcv,
                                                       const float* __restrict__ pe,
                                                       float* __restrict__ ck,
                                                       float* __restrict__ cv) {
  const int n = blockIdx.x / NHKV;
  const int h = blockIdx.x % NHKV;
  const int t = threadIdx.x;
  __shared__ float wk[CKS * DH];
  __shared__ float wv[CKS * DH];
  for (int e = t; e < CKS * DH; e += 128) {
    int s = e >> 7, dd = e & 127;
    size_t src = ((size_t)(n * CKST + s) * NHKV + h) * DH + dd;
    wk[e] = k[src] + pe[((size_t)h * CKS + s) * DH + dd];
    wv[e] = v[src];
  }
  __syncthreads();
  float ak0 = 0.f, ak1 = 0.f, av0 = 0.f, av1 = 0.f;
  const float* wckp = Wck + (size_t)h * CKS * DH * DH + t;
  const float* wcvp = Wcv + (size_t)h * CKS * DH * DH + t;
#pragma unroll 4
  for (int e = 0; e < CKS * DH; e += 2) {
    ak0 += wk[e] * wckp[(size_t)e * DH];
    av0 += wv[e] * wcvp[(size_t)e * DH];
    ak1 += wk[e + 1] * wckp[(size_t)(e + 1) * DH];
    av1 += wv[e + 1] * wcvp[(size_t)(e + 1) * DH];
  }
  ck[((size_t)n * NHKV + h) * DH + t] = ak0 + ak1;
  cv[((size_t)n * NHKV + h) * DH + t] = av0 + av1;
}

// ---------------- RoPE variants ----------------
// q: fp32 in-place + bf16 copy
__global__ __launch_bounds__(64) void rope_q_kernel(float* q, unsigned short* qbf) {
  const int rh = blockIdx.x;
  const int r = rh / NHQ;
  const int t = threadIdx.x;
  float* p = q + (size_t)rh * DH;
  float x1 = p[t], x2 = p[t + 64];
  float inv = powf(10000.f, -(float)t / 64.f);
  float ang = (float)r * inv;
  float c, s;
  sincosf(ang, &s, &c);
  float o1 = x1 * c - x2 * s;
  float o2 = x2 * c + x1 * s;
  p[t] = o1; p[t + 64] = o2;
  qbf[(size_t)rh * DH + t]      = f2bf(o1);
  qbf[(size_t)rh * DH + t + 64] = f2bf(o2);
}
// k: bf16 output only
__global__ __launch_bounds__(64) void rope_k_kernel(const float* kin, unsigned short* kbf) {
  const int rh = blockIdx.x;
  const int r = rh / NHKV;
  const int t = threadIdx.x;
  const float* p = kin + (size_t)rh * DH;
  float x1 = p[t], x2 = p[t + 64];
  float inv = powf(10000.f, -(float)t / 64.f);
  float ang = (float)r * inv;
  float c, s;
  sincosf(ang, &s, &c);
  kbf[(size_t)rh * DH + t]      = f2bf(x1 * c - x2 * s);
  kbf[(size_t)rh * DH + t + 64] = f2bf(x2 * c + x1 * s);
}
// ck: fp32 in-place, pos = r*CKST
__global__ __launch_bounds__(64) void rope_ck_kernel(float* ck) {
  const int rh = blockIdx.x;
  const int r = rh / NHKV;
  const int t = threadIdx.x;
  float* p = ck + (size_t)rh * DH;
  float x1 = p[t], x2 = p[t + 64];
  float inv = powf(10000.f, -(float)t / 64.f);
  float ang = (float)(r * CKST) * inv;
  float c, s;
  sincosf(ang, &s, &c);
  p[t]      = x1 * c - x2 * s;
  p[t + 64] = x2 * c + x1 * s;
}
// v: fp32 -> bf16
__global__ __launch_bounds__(256) void vconv_kernel(const float* __restrict__ v,
                                                    unsigned short* __restrict__ vbf) {
  const size_t u = (size_t)blockIdx.x * 256 + threadIdx.x;
  vbf[u] = f2bf(v[u]);
}

// ---------------- compressed attention + block top-k bitmask ----------------
__global__ __launch_bounds__(128) void cmp_attn_kernel(const float* __restrict__ q,
                                                       const float* __restrict__ ck,
                                                       const float* __restrict__ cv,
                                                       float* __restrict__ cmp_out,
                                                       unsigned* __restrict__ smask) {
  const int i = blockIdx.x;
  const int t = threadIdx.x;
  __shared__ float qs[DH];
  __shared__ float pbuf[128];
  __shared__ float red[128];
  __shared__ float pscore[NHKV][132];
  __shared__ float blks[NBLK];
  for (int h = 0; h < NHKV; ++h) {
    pscore[h][t] = 0.f;
    if (t < 4) pscore[h][128 + t] = 0.f;
  }
  int jmax = (i >= CKS - 1) ? ((i - (CKS - 1)) / CKST) : -1;
  if (jmax > NCMP - 1) jmax = NCMP - 1;
  __syncthreads();
  for (int h = 0; h < NHKV; ++h) {
    for (int g = 0; g < GQ; ++g) {
      const int hq = h * GQ + g;
      qs[t] = q[((size_t)i * NHQ + hq) * DH + t];
      __syncthreads();
      const bool valid = (t <= jmax);
      float val = -INFINITY;
      if (valid) {
        const float4* ckp = (const float4*)(ck + ((size_t)t * NHKV + h) * DH);
        float a0 = 0.f, a1 = 0.f;
#pragma unroll
        for (int d4 = 0; d4 < DH / 8; ++d4) {
          float4 k0 = ckp[2 * d4], k1 = ckp[2 * d4 + 1];
          a0 += qs[d4 * 8 + 0] * k0.x + qs[d4 * 8 + 1] * k0.y + qs[d4 * 8 + 2] * k0.z + qs[d4 * 8 + 3] * k0.w;
          a1 += qs[d4 * 8 + 4] * k1.x + qs[d4 * 8 + 5] * k1.y + qs[d4 * 8 + 6] * k1.z + qs[d4 * 8 + 7] * k1.w;
        }
        val = (a0 + a1) * SCALE;
      }
      red[t] = valid ? val : -INFINITY;
      __syncthreads();
      for (int s = 64; s > 0; s >>= 1) { if (t < s) red[t] = fmaxf(red[t], red[t + s]); __syncthreads(); }
      const float m = red[0];
      __syncthreads();
      const float e = valid ? expf(val - m) : 0.f;
      red[t] = e;
      __syncthreads();
      for (int s = 64; s > 0; s >>= 1) { if (t < s) red[t] += red[t + s]; __syncthreads(); }
      const float denom = fmaxf(red[0], 1e-20f);
      __syncthreads();
      const float p = e / denom;
      pbuf[t] = p;
      pscore[h][t] += p;
      __syncthreads();
      float acc0 = 0.f, acc1 = 0.f;
      const int nj = jmax + 1;
      for (int j = 0; j + 1 < nj; j += 2) {
        acc0 += pbuf[j] * cv[((size_t)j * NHKV + h) * DH + t];
        acc1 += pbuf[j + 1] * cv[((size_t)(j + 1) * NHKV + h) * DH + t];
      }
      if (nj & 1) acc0 += pbuf[nj - 1] * cv[((size_t)(nj - 1) * NHKV + h) * DH + t];
      cmp_out[((size_t)i * NHQ + hq) * DH + t] = acc0 + acc1;
      __syncthreads();
    }
  }
  const int qblk = i / BSZ;
  for (int h = 0; h < NHKV; ++h) {
    if (t < NBLK) {
      const float offw[5] = {1.f, 2.f, 2.f, 2.f, 1.f};
      float s = 0.f;
#pragma unroll
      for (int o = 0; o < 5; ++o) s += pscore[h][t * MBB + o] * offw[o];
      const bool causal = (t <= qblk);
      const bool forced = (t < 1) || ((t > qblk - 2) && causal);
      blks[t] = causal ? (forced ? INFINITY : s) : -INFINITY;
    }
    __syncthreads();
    if (t == 0) {
      float tmp[NBLK];
      for (int b = 0; b < NBLK; ++b) tmp[b] = blks[b];
      unsigned msk = 0;
      for (int s = 0; s < NTOP; ++s) {
        int best = -1;
        float bv = -INFINITY;
        for (int b = 0; b < NBLK; ++b)
          if (tmp[b] > bv) { bv = tmp[b]; best = b; }
        if (best >= 0) { msk |= (1u << best); tmp[best] = -INFINITY; }
      }
      smask[(size_t)i * NHKV + h] = msk;
    }
    __syncthreads();
  }
}

// ---------------- dual-mask flash attention (selected + window), bf16 MFMA ----------------
// block = 16 queries x 1 kv head; 4 waves; wave w owns 16 MFMA rows = 4 queries x 4 g.
constexpr int KSTR = 136;   // K-tile LDS stride (bf16 elems); 272B rows, 16B aligned
constexpr int VSTR = 40;    // Vt LDS stride; 80B rows
constexpr int PSTR = 40;    // P LDS stride

__global__ __launch_bounds__(256) void nsa_attn_kernel(
    const unsigned short* __restrict__ qbf,
    const unsigned short* __restrict__ kbf,
    const unsigned short* __restrict__ vbf,
    const unsigned* __restrict__ smask,
    const float* __restrict__ gate,
    const float* __restrict__ cmpo,
    float* __restrict__ outc) {
  __shared__ __align__(16) unsigned short Ks[32 * KSTR];
  __shared__ __align__(16) unsigned short Vts[128 * VSTR];
  __shared__ __align__(16) unsigned short Ps[4][2][16 * PSTR];
  const int bx = blockIdx.x;
  const int h = bx >> 7;
  const int qt = 127 - (bx & 127);      // big-work blocks dispatch first
  const int i0 = qt * 16;
  const int t = threadIdx.x;
  const int w = t >> 6;
  const int lane = t & 63;
  const int col = lane & 15;
  const int quad = lane >> 4;
  const int i0w = i0 + w * 4;
  const int i_lane = i0w + quad;        // this lane's query (C/D rows = 4 g's of it)

  // A-operand Q fragments: row m = col -> (query, g); k = quad*8 + dchunk*32
  short8 qf[4];
  {
    const int qi = i0w + (col >> 2);
    const int g = col & 3;
    const unsigned short* qp = qbf + (((size_t)qi * NHQ) + h * 4 + g) * DH + quad * 8;
#pragma unroll
    for (int dc = 0; dc < 4; ++dc) qf[dc] = *(const short8*)(qp + dc * 32);
  }
  const unsigned mymask = smask[(size_t)i_lane * NHKV + h];

  f32x4 accS[8], accW[8];
#pragma unroll
  for (int dt = 0; dt < 8; ++dt) { accS[dt] = f32x4{0.f,0.f,0.f,0.f}; accW[dt] = f32x4{0.f,0.f,0.f,0.f}; }
  float mS[4], mW[4], lS[4], lW[4];
#pragma unroll
  for (int r = 0; r < 4; ++r) { mS[r] = -INFINITY; mW[r] = -INFINITY; lS[r] = 0.f; lW[r] = 0.f; }

  const int ntile = (i0 + 16 + 31) >> 5;
  for (int tile = 0; tile < ntile; ++tile) {
    const int j0 = tile * 32;
    // stage K tile (32 keys x 128 d), row-major, coalesced
    {
      const int r = t >> 3, c = (t & 7) * 16;
      const unsigned short* src = kbf + ((size_t)((j0 + r) * NHKV + h)) * DH + c;
      *(short8*)(&Ks[r * KSTR + c])     = *(const short8*)(src);
      *(short8*)(&Ks[r * KSTR + c + 8]) = *(const short8*)(src + 8);
    }
    // stage V^T tile (128 d x 32 keys)
#pragma unroll
    for (int rep = 0; rep < 4; ++rep) {
      const int u = rep * 256 + t;
      const int j = u & 31, dg = u >> 5;
      us4 vv = *(const us4*)(vbf + ((size_t)((j0 + j) * NHKV + h)) * DH + dg * 4);
#pragma unroll
      for (int dd = 0; dd < 4; ++dd) Vts[(dg * 4 + dd) * VSTR + j] = vv[dd];
    }
    __syncthreads();

    const bool anywork = (j0 <= i0w + 3);
    const int blk = j0 >> 6;
    const bool selbit = anywork && ((mymask >> blk) & 1u);
    const bool selAny = (__ballot(selbit) != 0ull);
    const bool winAny = anywork && (j0 + 31 >= i0w - WINW);

    if (selAny || winAny) {
      // scores: S[m][n] for 16 rows x 32 keys
      f32x4 s0 = f32x4{0.f,0.f,0.f,0.f}, s1 = f32x4{0.f,0.f,0.f,0.f};
#pragma unroll
      for (int dc = 0; dc < 4; ++dc) {
        short8 kf0 = *(const short8*)(&Ks[(col)      * KSTR + dc * 32 + quad * 8]);
        short8 kf1 = *(const short8*)(&Ks[(16 + col) * KSTR + dc * 32 + quad * 8]);
        s0 = __builtin_amdgcn_mfma_f32_16x16x32_bf16(qf[dc], kf0, s0, 0, 0, 0);
        s1 = __builtin_amdgcn_mfma_f32_16x16x32_bf16(qf[dc], kf1, s1, 0, 0, 0);
      }
      const int jA = j0 + col, jB = j0 + 16 + col;
      const bool cA = (jA <= i_lane), cB = (jB <= i_lane);

      // ---- per-branch online softmax + P write ----
      auto dobranch = [&](bool bA, bool bB, float* mrun, float* lrun,
                          f32x4* acc, unsigned short* P) {
#pragma unroll
        for (int r = 0; r < 4; ++r) {
          float vA = bA ? s0[r] * SCALE : -INFINITY;
          float vB = bB ? s1[r] * SCALE : -INFINITY;
          float tm = fmaxf(vA, vB);
          tm = fmaxf(tm, __shfl_xor(tm, 1));
          tm = fmaxf(tm, __shfl_xor(tm, 2));
          tm = fmaxf(tm, __shfl_xor(tm, 4));
          tm = fmaxf(tm, __shfl_xor(tm, 8));
          float mn = fmaxf(mrun[r], tm);
          float a = (mn == -INFINITY) ? 1.f : __expf(mrun[r] - mn);
          float pA = bA ? __expf(vA - mn) : 0.f;
          float pB = bB ? __expf(vB - mn) : 0.f;
          lrun[r] = lrun[r] * a + pA + pB;
          mrun[r] = mn;
#pragma unroll
          for (int dt = 0; dt < 8; ++dt) acc[dt][r] *= a;
          P[(quad * 4 + r) * PSTR + col]      = f2bf(pA);
          P[(quad * 4 + r) * PSTR + 16 + col] = f2bf(pB);
        }
      };
      if (selAny) dobranch(selbit && cA, selbit && cB, mS, lS, accS, &Ps[w][0][0]);
      if (winAny) dobranch(cA && (jA >= i_lane - WINW), cB && (jB >= i_lane - WINW),
                           mW, lW, accW, &Ps[w][1][0]);

      // ---- PV MFMAs (V frags shared by both branches) ----
      short8 vf[8];
#pragma unroll
      for (int dt = 0; dt < 8; ++dt)
        vf[dt] = *(const short8*)(&Vts[(dt * 16 + col) * VSTR + quad * 8]);
      if (selAny) {
        short8 ap = *(const short8*)(&Ps[w][0][col * PSTR + quad * 8]);
#pragma unroll
        for (int dt = 0; dt < 8; ++dt)
          accS[dt] = __builtin_amdgcn_mfma_f32_16x16x32_bf16(ap, vf[dt], accS[dt], 0, 0, 0);
      }
      if (winAny) {
        short8 ap = *(const short8*)(&Ps[w][1][col * PSTR + quad * 8]);
#pragma unroll
        for (int dt = 0; dt < 8; ++dt)
          accW[dt] = __builtin_amdgcn_mfma_f32_16x16x32_bf16(ap, vf[dt], accW[dt], 0, 0, 0);
      }
    }
    __syncthreads();
  }

  // ---- epilogue: reduce l across the 16-lane groups, combine with gates + cmp ----
#pragma unroll
  for (int r = 0; r < 4; ++r) {
    float v = lS[r];
    v += __shfl_xor(v, 1); v += __shfl_xor(v, 2); v += __shfl_xor(v, 4); v += __shfl_xor(v, 8);
    lS[r] = v;
    float u = lW[r];
    u += __shfl_xor(u, 1); u += __shfl_xor(u, 2); u += __shfl_xor(u, 4); u += __shfl_xor(u, 8);
    lW[r] = u;
  }
  const float g0 = gate[i_lane * 3 + 0];
  const float g1 = gate[i_lane * 3 + 1];
  const float g2 = gate[i_lane * 3 + 2];
#pragma unroll
  for (int r = 0; r < 4; ++r) {
    const size_t base = ((size_t)i_lane * NHQ + h * 4 + r) * DH;
    const float rls = g1 / lS[r];
    const float rlw = g2 / lW[r];
#pragma unroll
    for (int dt = 0; dt < 8; ++dt) {
      const size_t o = base + dt * 16 + col;
      outc[o] = g0 * cmpo[o] + rls * accS[dt][r] + rlw * accW[dt][r];
    }
  }
}

// ---------------- launcher ----------------
extern "C" void kernel_launch(void* const* d_in, const int* in_sizes, int n_in,
                              void* d_out, int out_size, void* d_ws, size_t ws_size,
                              hipStream_t stream) {
  const float* x   = (const float*)d_in[0];
  const float* Wq  = (const float*)d_in[2];
  const float* Wk  = (const float*)d_in[3];
  const float* Wv  = (const float*)d_in[4];
  const float* Wo  = (const float*)d_in[5];
  const float* Wck = (const float*)d_in[6];
  const float* Wcv = (const float*)d_in[7];
  const float* pe  = (const float*)d_in[8];
  const float* Wg  = (const float*)d_in[9];
  float* out = (float*)d_out;

  float* ws = (float*)d_ws;
  float* q      = ws;                                    // 4194304
  float* kbuf   = q    + (size_t)SEQ * NHQ * DH;         // 1048576
  float* vbuf   = kbuf + (size_t)SEQ * NHKV * DH;        // 1048576
  float* ck     = vbuf + (size_t)SEQ * NHKV * DH;        // 65536 (pad)
  float* cv     = ck   + 65536;                          // 65536 (pad)
  float* gbuf   = cv   + 65536;                          // 8192
  float* cmpo   = gbuf + (size_t)SEQ * 4;                // 4194304
  unsigned* smask = (unsigned*)(cmpo + (size_t)SEQ * NHQ * DH);  // 8192 u32
  unsigned short* qbf = (unsigned short*)((float*)smask + 8192); // SEQ*NHQ*DH ushorts
  unsigned short* krbf = qbf + (size_t)SEQ * NHQ * DH;
  unsigned short* vbf  = krbf + (size_t)SEQ * NHKV * DH;
  float* comb = q;  // alias: fp32 q is dead after cmp_attn

  gemm_f32<<<dim3(NHQ * DH / 64, SEQ / 64), 256, 0, stream>>>(x, Wq, q, SEQ, NHQ * DH, HID);
  gemm_f32<<<dim3(NHKV * DH / 64, SEQ / 64), 256, 0, stream>>>(x, Wk, kbuf, SEQ, NHKV * DH, HID);
  gemm_f32<<<dim3(NHKV * DH / 64, SEQ / 64), 256, 0, stream>>>(x, Wv, vbuf, SEQ, NHKV * DH, HID);
  gate_kernel<<<SEQ, 128, 0, stream>>>(x, Wg, gbuf);
  compress_kernel<<<NCMP * NHKV, 128, 0, stream>>>(kbuf, vbuf, Wck, Wcv, pe, ck, cv);
  rope_q_kernel<<<SEQ * NHQ, 64, 0, stream>>>(q, qbf);
  rope_k_kernel<<<SEQ * NHKV, 64, 0, stream>>>(kbuf, krbf);
  rope_ck_kernel<<<NCMP * NHKV, 64, 0, stream>>>(ck);
  vconv_kernel<<<SEQ * NHKV * DH / 256, 256, 0, stream>>>(vbuf, vbf);
  cmp_attn_kernel<<<SEQ, 128, 0, stream>>>(q, ck, cv, cmpo, smask);
  nsa_attn_kernel<<<(SEQ / 16) * NHKV, 256, 0, stream>>>(qbf, krbf, vbf, smask, gbuf, cmpo, comb);
  gemm_f32<<<dim3(HID / 64, SEQ / 64), 256, 0, stream>>>(comb, Wo, out, SEQ, HID, NHQ * DH);
}

// Round 3
// 719.952 us; speedup vs baseline: 7.2051x; 2.1698x over previous
//
#include <hip/hip_runtime.h>
#include <math.h>

// ---------------- problem constants ----------------
constexpr int SEQ   = 2048;   // L
constexpr int HID   = 2048;
constexpr int NHQ   = 16;
constexpr int NHKV  = 4;
constexpr int GQ    = NHQ / NHKV;   // 4
constexpr int DH    = 128;
constexpr int CKS   = 32;     // compress window
constexpr int CKST  = 16;     // compress stride
constexpr int NCMP  = (SEQ - CKS) / CKST + 1;  // 127
constexpr int BSZ   = 64;     // selection block
constexpr int NTOP  = 16;
constexpr int NBLK  = SEQ / BSZ;   // 32
constexpr int MBB   = BSZ / CKST;  // 4
constexpr int WINW  = 512;
constexpr float SCALE = 0.08838834764831845f;  // 1/sqrt(128)

typedef __attribute__((ext_vector_type(8))) short short8;     // 8 bf16 (4 VGPRs)
typedef __attribute__((ext_vector_type(4))) float f32x4;
typedef __attribute__((ext_vector_type(4))) unsigned short us4;

static __device__ __forceinline__ unsigned short f2bf(float f) {
  unsigned u = __builtin_bit_cast(unsigned, f);
  u = (u + 0x7fffu + ((u >> 16) & 1u)) >> 16;
  return (unsigned short)u;
}
static __device__ __forceinline__ float bf2f(unsigned short u) {
  unsigned v = ((unsigned)u) << 16;
  return __builtin_bit_cast(float, v);
}

// ---------------- fp32 -> bf16 flat convert ----------------
__global__ __launch_bounds__(256) void conv_bf_kernel(const float* __restrict__ in,
                                                      unsigned short* __restrict__ out) {
  const size_t u = (size_t)blockIdx.x * 256 + threadIdx.x;
  out[u] = f2bf(in[u]);
}

// ---------------- fp32 [K][N] -> bf16 [N][K] tiled transpose ----------------
__global__ __launch_bounds__(256) void transpose_bf_kernel(const float* __restrict__ in,
                                                           unsigned short* __restrict__ out,
                                                           int K, int N) {
  __shared__ float tile[32][33];
  const int tx = threadIdx.x, ty = threadIdx.y;  // 32 x 8
  const int n0 = blockIdx.x * 32, k0 = blockIdx.y * 32;
#pragma unroll
  for (int r = 0; r < 4; ++r)
    tile[ty + 8 * r][tx] = in[(size_t)(k0 + ty + 8 * r) * N + n0 + tx];
  __syncthreads();
#pragma unroll
  for (int r = 0; r < 4; ++r)
    out[(size_t)(n0 + ty + 8 * r) * K + k0 + tx] = f2bf(tile[tx][ty + 8 * r]);
}

// ---------------- bf16 MFMA GEMM: C[M,N] fp32 = Abf[M,K] @ BtT[N,K]^T ----------------
// tile 128(M) x 64(N), BK=32, 256 threads = 4 waves, wave w owns rows [w*32, w*32+32)
__global__ __launch_bounds__(256) void gemm_bf16(const unsigned short* __restrict__ A,
                                                 const unsigned short* __restrict__ Bt,
                                                 float* __restrict__ C,
                                                 int M, int N, int K) {
  __shared__ __align__(16) unsigned short As[128 * 40];
  __shared__ __align__(16) unsigned short Bs[64 * 40];
  const int t = threadIdx.x;
  const int w = t >> 6;
  const int lane = t & 63;
  const int col = lane & 15;
  const int quad = lane >> 4;
  const int m0 = blockIdx.y * 128, n0 = blockIdx.x * 64;
  const int ra = t >> 1, ha = (t & 1) * 16;      // A staging: row, col-group
  const int rb = t >> 2, cb = (t & 3) * 8;       // B staging
  f32x4 acc[2][4];
#pragma unroll
  for (int mi = 0; mi < 2; ++mi)
#pragma unroll
    for (int ni = 0; ni < 4; ++ni) acc[mi][ni] = f32x4{0.f, 0.f, 0.f, 0.f};

  for (int k0 = 0; k0 < K; k0 += 32) {
    const unsigned short* sA = A + (size_t)(m0 + ra) * K + k0 + ha;
    *(short8*)&As[ra * 40 + ha]     = *(const short8*)sA;
    *(short8*)&As[ra * 40 + ha + 8] = *(const short8*)(sA + 8);
    const unsigned short* sB = Bt + (size_t)(n0 + rb) * K + k0 + cb;
    *(short8*)&Bs[rb * 40 + cb] = *(const short8*)sB;
    __syncthreads();
    short8 af[2], bfr[4];
#pragma unroll
    for (int mi = 0; mi < 2; ++mi)
      af[mi] = *(const short8*)&As[(w * 32 + mi * 16 + col) * 40 + quad * 8];
#pragma unroll
    for (int ni = 0; ni < 4; ++ni)
      bfr[ni] = *(const short8*)&Bs[(ni * 16 + col) * 40 + quad * 8];
#pragma unroll
    for (int mi = 0; mi < 2; ++mi)
#pragma unroll
      for (int ni = 0; ni < 4; ++ni)
        acc[mi][ni] = __builtin_amdgcn_mfma_f32_16x16x32_bf16(af[mi], bfr[ni], acc[mi][ni], 0, 0, 0);
    __syncthreads();
  }
#pragma unroll
  for (int mi = 0; mi < 2; ++mi)
#pragma unroll
    for (int ni = 0; ni < 4; ++ni)
#pragma unroll
      for (int r = 0; r < 4; ++r)
        C[(size_t)(m0 + w * 32 + mi * 16 + quad * 4 + r) * N + n0 + ni * 16 + col] = acc[mi][ni][r];
}

// ---------------- gate = sigmoid(x @ Wg) ----------------
__global__ __launch_bounds__(128) void gate_kernel(const float* __restrict__ x,
                                                   const float* __restrict__ Wg,
                                                   float* __restrict__ gate) {
  const int i = blockIdx.x;
  const int t = threadIdx.x;
  float a0 = 0.f, a1 = 0.f, a2 = 0.f;
  for (int k = t; k < HID; k += 128) {
    float xv = x[(size_t)i * HID + k];
    a0 += xv * Wg[k * 3 + 0];
    a1 += xv * Wg[k * 3 + 1];
    a2 += xv * Wg[k * 3 + 2];
  }
  __shared__ float r0[128], r1[128], r2[128];
  r0[t] = a0; r1[t] = a1; r2[t] = a2;
  __syncthreads();
  for (int s = 64; s > 0; s >>= 1) {
    if (t < s) { r0[t] += r0[t + s]; r1[t] += r1[t + s]; r2[t] += r2[t + s]; }
    __syncthreads();
  }
  if (t == 0) {
    gate[i * 3 + 0] = 1.f / (1.f + expf(-r0[0]));
    gate[i * 3 + 1] = 1.f / (1.f + expf(-r1[0]));
    gate[i * 3 + 2] = 1.f / (1.f + expf(-r2[0]));
  }
}

// ---------------- compression: ck fp32 (pre-rope) + cv bf16 ----------------
__global__ __launch_bounds__(128) void compress_kernel(const float* __restrict__ k,
                                                       const float* __restrict__ v,
                                                       const float* __restrict__ Wck,
                                                       const float* __restrict__ Wcv,
                                                       const float* __restrict__ pe,
                                                       float* __restrict__ ck,
                                                       unsigned short* __restrict__ cvbf) {
  const int n = blockIdx.x / NHKV;
  const int h = blockIdx.x % NHKV;
  const int t = threadIdx.x;
  __shared__ float wk[CKS * DH];
  __shared__ float wv[CKS * DH];
  for (int e = t; e < CKS * DH; e += 128) {
    int s = e >> 7, dd = e & 127;
    size_t src = ((size_t)(n * CKST + s) * NHKV + h) * DH + dd;
    wk[e] = k[src] + pe[((size_t)h * CKS + s) * DH + dd];
    wv[e] = v[src];
  }
  __syncthreads();
  float ak0 = 0.f, ak1 = 0.f, av0 = 0.f, av1 = 0.f;
  const float* wckp = Wck + (size_t)h * CKS * DH * DH + t;
  const float* wcvp = Wcv + (size_t)h * CKS * DH * DH + t;
#pragma unroll 4
  for (int e = 0; e < CKS * DH; e += 2) {
    ak0 += wk[e] * wckp[(size_t)e * DH];
    av0 += wv[e] * wcvp[(size_t)e * DH];
    ak1 += wk[e + 1] * wckp[(size_t)(e + 1) * DH];
    av1 += wv[e + 1] * wcvp[(size_t)(e + 1) * DH];
  }
  ck[((size_t)n * NHKV + h) * DH + t] = ak0 + ak1;
  cvbf[((size_t)n * NHKV + h) * DH + t] = f2bf(av0 + av1);
}

// ---------------- RoPE variants ----------------
__global__ __launch_bounds__(64) void rope_q_kernel(const float* __restrict__ q,
                                                    unsigned short* __restrict__ qbf) {
  const int rh = blockIdx.x;
  const int r = rh / NHQ;
  const int t = threadIdx.x;
  const float* p = q + (size_t)rh * DH;
  float x1 = p[t], x2 = p[t + 64];
  float inv = powf(10000.f, -(float)t / 64.f);
  float ang = (float)r * inv;
  float c, s;
  sincosf(ang, &s, &c);
  qbf[(size_t)rh * DH + t]      = f2bf(x1 * c - x2 * s);
  qbf[(size_t)rh * DH + t + 64] = f2bf(x2 * c + x1 * s);
}
__global__ __launch_bounds__(64) void rope_k_kernel(const float* __restrict__ kin,
                                                    unsigned short* __restrict__ kbf) {
  const int rh = blockIdx.x;
  const int r = rh / NHKV;
  const int t = threadIdx.x;
  const float* p = kin + (size_t)rh * DH;
  float x1 = p[t], x2 = p[t + 64];
  float inv = powf(10000.f, -(float)t / 64.f);
  float ang = (float)r * inv;
  float c, s;
  sincosf(ang, &s, &c);
  kbf[(size_t)rh * DH + t]      = f2bf(x1 * c - x2 * s);
  kbf[(size_t)rh * DH + t + 64] = f2bf(x2 * c + x1 * s);
}
__global__ __launch_bounds__(64) void rope_ck_kernel(const float* __restrict__ ck,
                                                     unsigned short* __restrict__ ckbf) {
  const int rh = blockIdx.x;
  const int r = rh / NHKV;
  const int t = threadIdx.x;
  const float* p = ck + (size_t)rh * DH;
  float x1 = p[t], x2 = p[t + 64];
  float inv = powf(10000.f, -(float)t / 64.f);
  float ang = (float)(r * CKST) * inv;
  float c, s;
  sincosf(ang, &s, &c);
  ckbf[(size_t)rh * DH + t]      = f2bf(x1 * c - x2 * s);
  ckbf[(size_t)rh * DH + t + 64] = f2bf(x2 * c + x1 * s);
}

// ---------------- MFMA compressed attention + pscore + top-k bitmask ----------------
// block = 16 queries x 1 kv head; 4 waves; wave w owns queries i0+4w..i0+4w+3 (x4 g)
constexpr int CSTR = 136;
__global__ __launch_bounds__(256) void cmp_attn_mfma(const unsigned short* __restrict__ qbf,
                                                     const unsigned short* __restrict__ ckbf,
                                                     const unsigned short* __restrict__ cvbf,
                                                     unsigned short* __restrict__ cmpobf,
                                                     unsigned* __restrict__ smask) {
  __shared__ __align__(16) unsigned short cks[64 * CSTR];    // one 64-key chunk
  __shared__ __align__(16) unsigned short cvts[128 * CSTR];  // V^T, all 128 key slots
  __shared__ __align__(16) unsigned short Ps[4][16 * CSTR];
  __shared__ float pscore[16][132];
  const int h = blockIdx.x & 3;
  const int i0 = (blockIdx.x >> 2) * 16;
  const int t = threadIdx.x;
  const int w = t >> 6;
  const int lane = t & 63;
  const int col = lane & 15;
  const int quad = lane >> 4;
  const int iq = i0 + 4 * w + quad;   // this lane's query for C-layout rows

  // Q A-frags: m=col -> (query, g)
  short8 qf[4];
  {
    const int qi = i0 + 4 * w + (col >> 2);
    const int g = col & 3;
    const unsigned short* qp = qbf + ((size_t)qi * NHQ + h * GQ + g) * DH + quad * 8;
#pragma unroll
    for (int dc = 0; dc < 4; ++dc) qf[dc] = *(const short8*)(qp + dc * 32);
  }
  if (t < 64) pscore[t >> 2][128 + (t & 3)] = 0.f;
  const int jmax = (iq >= CKS - 1) ? ((iq - (CKS - 1)) >> 4) : -1;  // <=126

  float sreg[8][4];
  for (int ch = 0; ch < 2; ++ch) {
    if (ch) __syncthreads();
    {  // stage 64 ck rows (keys ch*64 .. +63)
      const int r = t >> 2, c0 = (t & 3) * 32;
      const unsigned short* src = ckbf + ((size_t)(ch * 64 + r) * NHKV + h) * DH + c0;
#pragma unroll
      for (int u = 0; u < 4; ++u)
        *(short8*)&cks[r * CSTR + c0 + u * 8] = *(const short8*)(src + u * 8);
    }
    if (ch == 0) {  // stage cv^T once (zero pad key 127)
      const int j = t >> 1, d0 = (t & 1) * 64;
      const unsigned short* vsrc = cvbf + ((size_t)j * NHKV + h) * DH + d0;
#pragma unroll
      for (int u = 0; u < 16; ++u) {
        if (j == 127) {
#pragma unroll
          for (int dd = 0; dd < 4; ++dd) cvts[(d0 + u * 4 + dd) * CSTR + j] = 0;
        } else {
          us4 vv = *(const us4*)(vsrc + u * 4);
#pragma unroll
          for (int dd = 0; dd < 4; ++dd) cvts[(d0 + u * 4 + dd) * CSTR + j] = vv[dd];
        }
      }
    }
    __syncthreads();
#pragma unroll
    for (int tt = 0; tt < 4; ++tt) {
      f32x4 s = f32x4{0.f, 0.f, 0.f, 0.f};
#pragma unroll
      for (int dc = 0; dc < 4; ++dc)
        s = __builtin_amdgcn_mfma_f32_16x16x32_bf16(
            qf[dc], *(const short8*)&cks[(tt * 16 + col) * CSTR + dc * 32 + quad * 8], s, 0, 0, 0);
#pragma unroll
      for (int r = 0; r < 4; ++r) sreg[ch * 4 + tt][r] = s[r];
    }
  }

  // two-pass softmax per row r (g); key of a lane in tile tt = tt*16+col
#pragma unroll
  for (int r = 0; r < 4; ++r) {
    float mx = -INFINITY;
#pragma unroll
    for (int tt = 0; tt < 8; ++tt) {
      const float val = (tt * 16 + col <= jmax) ? sreg[tt][r] * SCALE : -INFINITY;
      sreg[tt][r] = val;
      mx = fmaxf(mx, val);
    }
    mx = fmaxf(mx, __shfl_xor(mx, 1));
    mx = fmaxf(mx, __shfl_xor(mx, 2));
    mx = fmaxf(mx, __shfl_xor(mx, 4));
    mx = fmaxf(mx, __shfl_xor(mx, 8));
    float l = 0.f;
#pragma unroll
    for (int tt = 0; tt < 8; ++tt) {
      const float p = (sreg[tt][r] == -INFINITY) ? 0.f : __expf(sreg[tt][r] - mx);
      sreg[tt][r] = p;
      l += p;
    }
    l += __shfl_xor(l, 1); l += __shfl_xor(l, 2); l += __shfl_xor(l, 4); l += __shfl_xor(l, 8);
    const float rden = 1.f / fmaxf(l, 1e-20f);
#pragma unroll
    for (int tt = 0; tt < 8; ++tt) {
      const float pn = sreg[tt][r] * rden;
      sreg[tt][r] = pn;
      Ps[w][(quad * 4 + r) * CSTR + tt * 16 + col] = f2bf(pn);
    }
  }
#pragma unroll
  for (int tt = 0; tt < 8; ++tt)
    pscore[4 * w + quad][tt * 16 + col] = sreg[tt][0] + sreg[tt][1] + sreg[tt][2] + sreg[tt][3];

  // PV
  f32x4 acc[8];
#pragma unroll
  for (int dt = 0; dt < 8; ++dt) acc[dt] = f32x4{0.f, 0.f, 0.f, 0.f};
#pragma unroll
  for (int kt = 0; kt < 4; ++kt) {
    short8 ap = *(const short8*)&Ps[w][col * CSTR + kt * 32 + quad * 8];
#pragma unroll
    for (int dt = 0; dt < 8; ++dt)
      acc[dt] = __builtin_amdgcn_mfma_f32_16x16x32_bf16(
          ap, *(const short8*)&cvts[(dt * 16 + col) * CSTR + kt * 32 + quad * 8], acc[dt], 0, 0, 0);
  }
#pragma unroll
  for (int dt = 0; dt < 8; ++dt)
#pragma unroll
    for (int r = 0; r < 4; ++r)
      cmpobf[((size_t)iq * NHQ + h * GQ + r) * DH + dt * 16 + col] = f2bf(acc[dt][r]);

  __syncthreads();
  // block scores + top-16 per query (16 threads)
  if (t < 16) {
    const int i = i0 + t;
    const int qblk = i / BSZ;
    const float offw[5] = {1.f, 2.f, 2.f, 2.f, 1.f};
    float tmp[NBLK];
    for (int b = 0; b < NBLK; ++b) {
      float s = 0.f;
#pragma unroll
      for (int o = 0; o < 5; ++o) s += pscore[t][b * MBB + o] * offw[o];
      const bool causal = (b <= qblk);
      const bool forced = (b < 1) || ((b > qblk - 2) && causal);
      tmp[b] = causal ? (forced ? INFINITY : s) : -INFINITY;
    }
    unsigned msk = 0;
    for (int s = 0; s < NTOP; ++s) {
      int best = -1;
      float bv = -INFINITY;
      for (int b = 0; b < NBLK; ++b)
        if (tmp[b] > bv) { bv = tmp[b]; best = b; }
      if (best >= 0) { msk |= (1u << best); tmp[best] = -INFINITY; }
    }
    smask[(size_t)i * NHKV + h] = msk;
  }
}

// ---------------- dual-mask flash attention (selected + window), bf16 MFMA ----------------
constexpr int KSTR = 136;
constexpr int VSTR = 40;
constexpr int PSTR = 40;

__global__ __launch_bounds__(256) void nsa_attn_kernel(
    const unsigned short* __restrict__ qbf,
    const unsigned short* __restrict__ kbf,
    const unsigned short* __restrict__ vbf,
    const unsigned* __restrict__ smask,
    const float* __restrict__ gate,
    const unsigned short* __restrict__ cmpo,
    unsigned short* __restrict__ outc) {
  __shared__ __align__(16) unsigned short Ks[32 * KSTR];
  __shared__ __align__(16) unsigned short Vts[128 * VSTR];
  __shared__ __align__(16) unsigned short Ps[4][2][16 * PSTR];
  const int bx = blockIdx.x;
  const int h = bx >> 7;
  const int qt = 127 - (bx & 127);
  const int i0 = qt * 16;
  const int t = threadIdx.x;
  const int w = t >> 6;
  const int lane = t & 63;
  const int col = lane & 15;
  const int quad = lane >> 4;
  const int i0w = i0 + w * 4;
  const int i_lane = i0w + quad;

  short8 qf[4];
  {
    const int qi = i0w + (col >> 2);
    const int g = col & 3;
    const unsigned short* qp = qbf + (((size_t)qi * NHQ) + h * 4 + g) * DH + quad * 8;
#pragma unroll
    for (int dc = 0; dc < 4; ++dc) qf[dc] = *(const short8*)(qp + dc * 32);
  }
  const unsigned mymask = smask[(size_t)i_lane * NHKV + h];

  f32x4 accS[8], accW[8];
#pragma unroll
  for (int dt = 0; dt < 8; ++dt) { accS[dt] = f32x4{0.f,0.f,0.f,0.f}; accW[dt] = f32x4{0.f,0.f,0.f,0.f}; }
  float mS[4], mW[4], lS[4], lW[4];
#pragma unroll
  for (int r = 0; r < 4; ++r) { mS[r] = -INFINITY; mW[r] = -INFINITY; lS[r] = 0.f; lW[r] = 0.f; }

  const int ntile = (i0 + 16 + 31) >> 5;
  for (int tile = 0; tile < ntile; ++tile) {
    const int j0 = tile * 32;
    {
      const int r = t >> 3, c = (t & 7) * 16;
      const unsigned short* src = kbf + ((size_t)((j0 + r) * NHKV + h)) * DH + c;
      *(short8*)(&Ks[r * KSTR + c])     = *(const short8*)(src);
      *(short8*)(&Ks[r * KSTR + c + 8]) = *(const short8*)(src + 8);
    }
#pragma unroll
    for (int rep = 0; rep < 4; ++rep) {
      const int u = rep * 256 + t;
      const int j = u & 31, dg = u >> 5;
      us4 vv = *(const us4*)(vbf + ((size_t)((j0 + j) * NHKV + h)) * DH + dg * 4);
#pragma unroll
      for (int dd = 0; dd < 4; ++dd) Vts[(dg * 4 + dd) * VSTR + j] = vv[dd];
    }
    __syncthreads();

    const bool anywork = (j0 <= i0w + 3);
    const int blk = j0 >> 6;
    const bool selbit = anywork && ((mymask >> blk) & 1u);
    const bool selAny = (__ballot(selbit) != 0ull);
    const bool winAny = anywork && (j0 + 31 >= i0w - WINW);

    if (selAny || winAny) {
      f32x4 s0 = f32x4{0.f,0.f,0.f,0.f}, s1 = f32x4{0.f,0.f,0.f,0.f};
#pragma unroll
      for (int dc = 0; dc < 4; ++dc) {
        short8 kf0 = *(const short8*)(&Ks[(col)      * KSTR + dc * 32 + quad * 8]);
        short8 kf1 = *(const short8*)(&Ks[(16 + col) * KSTR + dc * 32 + quad * 8]);
        s0 = __builtin_amdgcn_mfma_f32_16x16x32_bf16(qf[dc], kf0, s0, 0, 0, 0);
        s1 = __builtin_amdgcn_mfma_f32_16x16x32_bf16(qf[dc], kf1, s1, 0, 0, 0);
      }
      const int jA = j0 + col, jB = j0 + 16 + col;
      const bool cA = (jA <= i_lane), cB = (jB <= i_lane);

      auto dobranch = [&](bool bA, bool bB, float* mrun, float* lrun,
                          f32x4* acc, unsigned short* P) {
#pragma unroll
        for (int r = 0; r < 4; ++r) {
          float vA = bA ? s0[r] * SCALE : -INFINITY;
          float vB = bB ? s1[r] * SCALE : -INFINITY;
          float tm = fmaxf(vA, vB);
          tm = fmaxf(tm, __shfl_xor(tm, 1));
          tm = fmaxf(tm, __shfl_xor(tm, 2));
          tm = fmaxf(tm, __shfl_xor(tm, 4));
          tm = fmaxf(tm, __shfl_xor(tm, 8));
          float mn = fmaxf(mrun[r], tm);
          float a = (mn == -INFINITY) ? 1.f : __expf(mrun[r] - mn);
          float pA = bA ? __expf(vA - mn) : 0.f;
          float pB = bB ? __expf(vB - mn) : 0.f;
          lrun[r] = lrun[r] * a + pA + pB;
          mrun[r] = mn;
#pragma unroll
          for (int dt = 0; dt < 8; ++dt) acc[dt][r] *= a;
          P[(quad * 4 + r) * PSTR + col]      = f2bf(pA);
          P[(quad * 4 + r) * PSTR + 16 + col] = f2bf(pB);
        }
      };
      if (selAny) dobranch(selbit && cA, selbit && cB, mS, lS, accS, &Ps[w][0][0]);
      if (winAny) dobranch(cA && (jA >= i_lane - WINW), cB && (jB >= i_lane - WINW),
                           mW, lW, accW, &Ps[w][1][0]);

      short8 vf[8];
#pragma unroll
      for (int dt = 0; dt < 8; ++dt)
        vf[dt] = *(const short8*)(&Vts[(dt * 16 + col) * VSTR + quad * 8]);
      if (selAny) {
        short8 ap = *(const short8*)(&Ps[w][0][col * PSTR + quad * 8]);
#pragma unroll
        for (int dt = 0; dt < 8; ++dt)
          accS[dt] = __builtin_amdgcn_mfma_f32_16x16x32_bf16(ap, vf[dt], accS[dt], 0, 0, 0);
      }
      if (winAny) {
        short8 ap = *(const short8*)(&Ps[w][1][col * PSTR + quad * 8]);
#pragma unroll
        for (int dt = 0; dt < 8; ++dt)
          accW[dt] = __builtin_amdgcn_mfma_f32_16x16x32_bf16(ap, vf[dt], accW[dt], 0, 0, 0);
      }
    }
    __syncthreads();
  }

#pragma unroll
  for (int r = 0; r < 4; ++r) {
    float v = lS[r];
    v += __shfl_xor(v, 1); v += __shfl_xor(v, 2); v += __shfl_xor(v, 4); v += __shfl_xor(v, 8);
    lS[r] = v;
    float u = lW[r];
    u += __shfl_xor(u, 1); u += __shfl_xor(u, 2); u += __shfl_xor(u, 4); u += __shfl_xor(u, 8);
    lW[r] = u;
  }
  const float g0 = gate[i_lane * 3 + 0];
  const float g1 = gate[i_lane * 3 + 1];
  const float g2 = gate[i_lane * 3 + 2];
#pragma unroll
  for (int r = 0; r < 4; ++r) {
    const size_t base = ((size_t)i_lane * NHQ + h * 4 + r) * DH;
    const float rls = g1 / lS[r];
    const float rlw = g2 / lW[r];
#pragma unroll
    for (int dt = 0; dt < 8; ++dt) {
      const size_t o = base + dt * 16 + col;
      outc[o] = f2bf(g0 * bf2f(cmpo[o]) + rls * accS[dt][r] + rlw * accW[dt][r]);
    }
  }
}

// ---------------- launcher ----------------
extern "C" void kernel_launch(void* const* d_in, const int* in_sizes, int n_in,
                              void* d_out, int out_size, void* d_ws, size_t ws_size,
                              hipStream_t stream) {
  const float* x   = (const float*)d_in[0];
  const float* Wq  = (const float*)d_in[2];
  const float* Wk  = (const float*)d_in[3];
  const float* Wv  = (const float*)d_in[4];
  const float* Wo  = (const float*)d_in[5];
  const float* Wck = (const float*)d_in[6];
  const float* Wcv = (const float*)d_in[7];
  const float* pe  = (const float*)d_in[8];
  const float* Wg  = (const float*)d_in[9];
  float* out = (float*)d_out;

  // workspace layout with phase-based aliasing
  unsigned char* p = (unsigned char*)d_ws;
  auto alloc = [&](size_t bytes) { void* r = p; p += (bytes + 255) & ~(size_t)255; return r; };
  float* q    = (float*)alloc((size_t)SEQ * NHQ * DH * 4);    // dead after rope_q -> hosts WoT
  float* kbuf = (float*)alloc((size_t)SEQ * NHKV * DH * 4);   // kbuf+vbuf -> hosts combbf later
  float* vbuf = (float*)alloc((size_t)SEQ * NHKV * DH * 4);
  float* ck   = (float*)alloc((size_t)128 * NHKV * DH * 4);   // 128 rows (pad)
  float* gbuf = (float*)alloc((size_t)SEQ * 4 * 4);
  unsigned* smask = (unsigned*)alloc((size_t)SEQ * NHKV * 4);
  unsigned short* ckbf = (unsigned short*)alloc((size_t)128 * NHKV * DH * 2);
  unsigned short* cvbf = (unsigned short*)alloc((size_t)128 * NHKV * DH * 2);
  unsigned short* xbf  = (unsigned short*)alloc((size_t)SEQ * HID * 2);       // dead after gemms -> cmpobf
  unsigned short* WqT  = (unsigned short*)alloc((size_t)NHQ * DH * HID * 2);  // dead after gemm q -> qbf
  unsigned short* WkT  = (unsigned short*)alloc((size_t)NHKV * DH * HID * 2); // -> krbf
  unsigned short* WvT  = (unsigned short*)alloc((size_t)NHKV * DH * HID * 2); // -> vbf
  unsigned short* WoT    = (unsigned short*)q;
  unsigned short* combbf = (unsigned short*)kbuf;   // kbuf+vbuf = exactly 2048*2048*2 bytes
  unsigned short* cmpobf = xbf;
  unsigned short* qbf  = WqT;
  unsigned short* krbf = WkT;
  unsigned short* vbf  = WvT;

  // convert / transpose weights + x
  conv_bf_kernel<<<(SEQ * HID) / 256, 256, 0, stream>>>(x, xbf);
  transpose_bf_kernel<<<dim3((NHQ * DH) / 32, HID / 32), dim3(32, 8), 0, stream>>>(Wq, WqT, HID, NHQ * DH);
  transpose_bf_kernel<<<dim3((NHKV * DH) / 32, HID / 32), dim3(32, 8), 0, stream>>>(Wk, WkT, HID, NHKV * DH);
  transpose_bf_kernel<<<dim3((NHKV * DH) / 32, HID / 32), dim3(32, 8), 0, stream>>>(Wv, WvT, HID, NHKV * DH);
  // projections (bf16 MFMA)
  gemm_bf16<<<dim3((NHQ * DH) / 64, SEQ / 128), 256, 0, stream>>>(xbf, WqT, q, SEQ, NHQ * DH, HID);
  gemm_bf16<<<dim3((NHKV * DH) / 64, SEQ / 128), 256, 0, stream>>>(xbf, WkT, kbuf, SEQ, NHKV * DH, HID);
  gemm_bf16<<<dim3((NHKV * DH) / 64, SEQ / 128), 256, 0, stream>>>(xbf, WvT, vbuf, SEQ, NHKV * DH, HID);
  gate_kernel<<<SEQ, 128, 0, stream>>>(x, Wg, gbuf);
  // compression
  compress_kernel<<<NCMP * NHKV, 128, 0, stream>>>(kbuf, vbuf, Wck, Wcv, pe, ck, cvbf);
  // RoPE + conversions (qbf overwrites WqT only after gemm q done)
  rope_q_kernel<<<SEQ * NHQ, 64, 0, stream>>>(q, qbf);
  transpose_bf_kernel<<<dim3(HID / 32, (NHQ * DH) / 32), dim3(32, 8), 0, stream>>>(Wo, WoT, NHQ * DH, HID);
  rope_k_kernel<<<SEQ * NHKV, 64, 0, stream>>>(kbuf, krbf);
  rope_ck_kernel<<<NCMP * NHKV, 64, 0, stream>>>(ck, ckbf);
  conv_bf_kernel<<<(SEQ * NHKV * DH) / 256, 256, 0, stream>>>(vbuf, vbf);
  // compressed attention + selection
  cmp_attn_mfma<<<(SEQ / 16) * NHKV, 256, 0, stream>>>(qbf, ckbf, cvbf, cmpobf, smask);
  // selected + window attention + gated combine (writes combbf over dead kbuf/vbuf)
  nsa_attn_kernel<<<(SEQ / 16) * NHKV, 256, 0, stream>>>(qbf, krbf, vbf, smask, gbuf, cmpobf, combbf);
  // output projection
  gemm_bf16<<<dim3(HID / 64, SEQ / 128), 256, 0, stream>>>(combbf, WoT, out, SEQ, HID, NHQ * DH);
}

// Round 4
// 617.847 us; speedup vs baseline: 8.3958x; 1.1653x over previous
//
#include <hip/hip_runtime.h>
#include <math.h>

// ---------------- problem constants ----------------
constexpr int SEQ   = 2048;   // L
constexpr int HID   = 2048;
constexpr int NHQ   = 16;
constexpr int NHKV  = 4;
constexpr int GQ    = NHQ / NHKV;   // 4
constexpr int DH    = 128;
constexpr int CKS   = 32;     // compress window
constexpr int CKST  = 16;     // compress stride
constexpr int NCMP  = (SEQ - CKS) / CKST + 1;  // 127
constexpr int BSZ   = 64;     // selection block
constexpr int NTOP  = 16;
constexpr int NBLK  = SEQ / BSZ;   // 32
constexpr int MBB   = BSZ / CKST;  // 4
constexpr int WINW  = 512;
constexpr int CKD   = CKS * DH;    // 4096 = compress GEMM K
constexpr float SCALE = 0.08838834764831845f;  // 1/sqrt(128)

typedef __attribute__((ext_vector_type(8))) short short8;     // 8 bf16 (4 VGPRs)
typedef __attribute__((ext_vector_type(4))) float f32x4;
typedef __attribute__((ext_vector_type(4))) unsigned short us4;

static __device__ __forceinline__ unsigned short f2bf(float f) {
  unsigned u = __builtin_bit_cast(unsigned, f);
  u = (u + 0x7fffu + ((u >> 16) & 1u)) >> 16;
  return (unsigned short)u;
}
static __device__ __forceinline__ float bf2f(unsigned short u) {
  unsigned v = ((unsigned)u) << 16;
  return __builtin_bit_cast(float, v);
}

// ---------------- fp32 -> bf16 flat convert ----------------
__global__ __launch_bounds__(256) void conv_bf_kernel(const float* __restrict__ in,
                                                      unsigned short* __restrict__ out) {
  const size_t u = (size_t)blockIdx.x * 256 + threadIdx.x;
  out[u] = f2bf(in[u]);
}

// ---------------- fp32 [K][N] -> bf16 [N][K] tiled transpose (batched over z) ----------------
__global__ __launch_bounds__(256) void transpose_bf_kernel(const float* __restrict__ in,
                                                           unsigned short* __restrict__ out,
                                                           int K, int N) {
  __shared__ float tile[32][33];
  const int tx = threadIdx.x, ty = threadIdx.y;  // 32 x 8
  const int n0 = blockIdx.x * 32, k0 = blockIdx.y * 32;
  const size_t zo = (size_t)blockIdx.z * K * N;
  const float* inz = in + zo;
  unsigned short* outz = out + zo;
#pragma unroll
  for (int r = 0; r < 4; ++r)
    tile[ty + 8 * r][tx] = inz[(size_t)(k0 + ty + 8 * r) * N + n0 + tx];
  __syncthreads();
#pragma unroll
  for (int r = 0; r < 4; ++r)
    outz[(size_t)(n0 + ty + 8 * r) * K + k0 + tx] = f2bf(tile[tx][ty + 8 * r]);
}

// ---------------- bf16 MFMA GEMM, 128x128 tile: C[M,N] fp32 = A[M,K] @ Bt[N,K]^T ----------------
// 256 threads = 4 waves; wave w owns rows [w*32, w*32+32); 2x8 MFMA per K-step (BK=32)
__global__ __launch_bounds__(256) void gemm_bf16_128(const unsigned short* __restrict__ A,
                                                     const unsigned short* __restrict__ Bt,
                                                     float* __restrict__ C,
                                                     int M, int N, int K) {
  __shared__ __align__(16) unsigned short As[128 * 40];
  __shared__ __align__(16) unsigned short Bs[128 * 40];
  const int t = threadIdx.x;
  const int w = t >> 6;
  const int lane = t & 63;
  const int col = lane & 15;
  const int quad = lane >> 4;
  const int m0 = blockIdx.y * 128, n0 = blockIdx.x * 128;
  const int ra = t >> 1, ha = (t & 1) * 16;
  f32x4 acc[2][8];
#pragma unroll
  for (int mi = 0; mi < 2; ++mi)
#pragma unroll
    for (int ni = 0; ni < 8; ++ni) acc[mi][ni] = f32x4{0.f, 0.f, 0.f, 0.f};

  for (int k0 = 0; k0 < K; k0 += 32) {
    const unsigned short* sA = A + (size_t)(m0 + ra) * K + k0 + ha;
    *(short8*)&As[ra * 40 + ha]     = *(const short8*)sA;
    *(short8*)&As[ra * 40 + ha + 8] = *(const short8*)(sA + 8);
    const unsigned short* sB = Bt + (size_t)(n0 + ra) * K + k0 + ha;
    *(short8*)&Bs[ra * 40 + ha]     = *(const short8*)sB;
    *(short8*)&Bs[ra * 40 + ha + 8] = *(const short8*)(sB + 8);
    __syncthreads();
    short8 af[2], bfr[8];
#pragma unroll
    for (int mi = 0; mi < 2; ++mi)
      af[mi] = *(const short8*)&As[(w * 32 + mi * 16 + col) * 40 + quad * 8];
#pragma unroll
    for (int ni = 0; ni < 8; ++ni)
      bfr[ni] = *(const short8*)&Bs[(ni * 16 + col) * 40 + quad * 8];
#pragma unroll
    for (int mi = 0; mi < 2; ++mi)
#pragma unroll
      for (int ni = 0; ni < 8; ++ni)
        acc[mi][ni] = __builtin_amdgcn_mfma_f32_16x16x32_bf16(af[mi], bfr[ni], acc[mi][ni], 0, 0, 0);
    __syncthreads();
  }
#pragma unroll
  for (int mi = 0; mi < 2; ++mi)
#pragma unroll
    for (int ni = 0; ni < 8; ++ni)
#pragma unroll
      for (int r = 0; r < 4; ++r)
        C[(size_t)(m0 + w * 32 + mi * 16 + quad * 4 + r) * N + n0 + ni * 16 + col] = acc[mi][ni][r];
}

// ---------------- compress A-build: Ak/Av[h][128][4096] bf16 ----------------
__global__ __launch_bounds__(256) void abuild_kernel(const float* __restrict__ k,
                                                     const float* __restrict__ v,
                                                     const float* __restrict__ pe,
                                                     unsigned short* __restrict__ Ak,
                                                     unsigned short* __restrict__ Av) {
  const size_t u = (size_t)blockIdx.x * 256 + threadIdx.x;  // < 4*128*4096
  const int h = (int)(u >> 19);
  const int rem = (int)(u & 524287);
  const int n = rem >> 12;
  const int e = rem & 4095;
  const int s = e >> 7;
  const int d = e & 127;
  const size_t src = ((size_t)(n * CKST + s) * NHKV + h) * DH + d;
  Ak[u] = f2bf(k[src] + pe[((size_t)h * CKS + s) * DH + d]);
  Av[u] = f2bf(v[src]);
}

// ---------------- compress GEMM (split-K partials): z = mat*16 + h*4 + kc ----------------
// per block: Cpart[z][128][128] += A[h][128][kc*1024..+1024] @ Wt[h][128][same]^T
__global__ __launch_bounds__(256) void compress_gemm(const unsigned short* __restrict__ Ak,
                                                     const unsigned short* __restrict__ Av,
                                                     const unsigned short* __restrict__ WckT,
                                                     const unsigned short* __restrict__ WcvT,
                                                     float* __restrict__ Cpart) {
  __shared__ __align__(16) unsigned short As[128 * 40];
  __shared__ __align__(16) unsigned short Bs[128 * 40];
  const int z = blockIdx.x;
  const int mat = z >> 4;
  const int h = (z >> 2) & 3;
  const int kc = z & 3;
  const unsigned short* A  = (mat ? Av : Ak)   + (size_t)h * 128 * CKD;
  const unsigned short* Bt = (mat ? WcvT : WckT) + (size_t)h * DH * CKD;
  float* Cout = Cpart + (size_t)z * 128 * 128;
  const int t = threadIdx.x;
  const int w = t >> 6;
  const int lane = t & 63;
  const int col = lane & 15;
  const int quad = lane >> 4;
  const int ra = t >> 1, ha = (t & 1) * 16;
  f32x4 acc[2][8];
#pragma unroll
  for (int mi = 0; mi < 2; ++mi)
#pragma unroll
    for (int ni = 0; ni < 8; ++ni) acc[mi][ni] = f32x4{0.f, 0.f, 0.f, 0.f};
  for (int k0 = kc * 1024; k0 < kc * 1024 + 1024; k0 += 32) {
    const unsigned short* sA = A + (size_t)ra * CKD + k0 + ha;
    *(short8*)&As[ra * 40 + ha]     = *(const short8*)sA;
    *(short8*)&As[ra * 40 + ha + 8] = *(const short8*)(sA + 8);
    const unsigned short* sB = Bt + (size_t)ra * CKD + k0 + ha;
    *(short8*)&Bs[ra * 40 + ha]     = *(const short8*)sB;
    *(short8*)&Bs[ra * 40 + ha + 8] = *(const short8*)(sB + 8);
    __syncthreads();
    short8 af[2], bfr[8];
#pragma unroll
    for (int mi = 0; mi < 2; ++mi)
      af[mi] = *(const short8*)&As[(w * 32 + mi * 16 + col) * 40 + quad * 8];
#pragma unroll
    for (int ni = 0; ni < 8; ++ni)
      bfr[ni] = *(const short8*)&Bs[(ni * 16 + col) * 40 + quad * 8];
#pragma unroll
    for (int mi = 0; mi < 2; ++mi)
#pragma unroll
      for (int ni = 0; ni < 8; ++ni)
        acc[mi][ni] = __builtin_amdgcn_mfma_f32_16x16x32_bf16(af[mi], bfr[ni], acc[mi][ni], 0, 0, 0);
    __syncthreads();
  }
#pragma unroll
  for (int mi = 0; mi < 2; ++mi)
#pragma unroll
    for (int ni = 0; ni < 8; ++ni)
#pragma unroll
      for (int r = 0; r < 4; ++r)
        Cout[(size_t)(w * 32 + mi * 16 + quad * 4 + r) * 128 + ni * 16 + col] = acc[mi][ni][r];
}

// ---------------- compress reduce: sum 4 K-chunks -> ck fp32 / cv bf16 ----------------
__global__ __launch_bounds__(256) void compress_reduce(const float* __restrict__ Cpart,
                                                       float* __restrict__ ck,
                                                       unsigned short* __restrict__ cvbf) {
  const unsigned u = blockIdx.x * 256 + threadIdx.x;  // < 2*4*128*128
  const int mat = u >> 16;
  const int rem = u & 65535;
  const int h = rem >> 14;
  const int rem2 = rem & 16383;
  const int n = rem2 >> 7;
  const int d = rem2 & 127;
  const size_t base = ((size_t)(mat * 16 + h * 4) << 14) + rem2;
  float s = Cpart[base] + Cpart[base + 16384] + Cpart[base + 2 * 16384] + Cpart[base + 3 * 16384];
  const size_t o = ((size_t)n * NHKV + h) * DH + d;
  if (mat == 0) ck[o] = s;
  else cvbf[o] = f2bf(s);
}

// ---------------- gate = sigmoid(x @ Wg), wave-shuffle reduce ----------------
__global__ __launch_bounds__(128) void gate_kernel(const float* __restrict__ x,
                                                   const float* __restrict__ Wg,
                                                   float* __restrict__ gate) {
  const int i = blockIdx.x;
  const int t = threadIdx.x;
  float a0 = 0.f, a1 = 0.f, a2 = 0.f;
  for (int kk = t; kk < HID; kk += 128) {
    float xv = x[(size_t)i * HID + kk];
    a0 += xv * Wg[kk * 3 + 0];
    a1 += xv * Wg[kk * 3 + 1];
    a2 += xv * Wg[kk * 3 + 2];
  }
#pragma unroll
  for (int s = 1; s < 64; s <<= 1) {
    a0 += __shfl_xor(a0, s);
    a1 += __shfl_xor(a1, s);
    a2 += __shfl_xor(a2, s);
  }
  __shared__ float part[2][3];
  if ((t & 63) == 0) { part[t >> 6][0] = a0; part[t >> 6][1] = a1; part[t >> 6][2] = a2; }
  __syncthreads();
  if (t == 0) {
    gate[i * 3 + 0] = 1.f / (1.f + expf(-(part[0][0] + part[1][0])));
    gate[i * 3 + 1] = 1.f / (1.f + expf(-(part[0][1] + part[1][1])));
    gate[i * 3 + 2] = 1.f / (1.f + expf(-(part[0][2] + part[1][2])));
  }
}

// ---------------- RoPE variants ----------------
__global__ __launch_bounds__(64) void rope_q_kernel(const float* __restrict__ q,
                                                    unsigned short* __restrict__ qbf) {
  const int rh = blockIdx.x;
  const int r = rh / NHQ;
  const int t = threadIdx.x;
  const float* p = q + (size_t)rh * DH;
  float x1 = p[t], x2 = p[t + 64];
  float inv = powf(10000.f, -(float)t / 64.f);
  float ang = (float)r * inv;
  float c, s;
  sincosf(ang, &s, &c);
  qbf[(size_t)rh * DH + t]      = f2bf(x1 * c - x2 * s);
  qbf[(size_t)rh * DH + t + 64] = f2bf(x2 * c + x1 * s);
}
__global__ __launch_bounds__(64) void rope_k_kernel(const float* __restrict__ kin,
                                                    unsigned short* __restrict__ kbf) {
  const int rh = blockIdx.x;
  const int r = rh / NHKV;
  const int t = threadIdx.x;
  const float* p = kin + (size_t)rh * DH;
  float x1 = p[t], x2 = p[t + 64];
  float inv = powf(10000.f, -(float)t / 64.f);
  float ang = (float)r * inv;
  float c, s;
  sincosf(ang, &s, &c);
  kbf[(size_t)rh * DH + t]      = f2bf(x1 * c - x2 * s);
  kbf[(size_t)rh * DH + t + 64] = f2bf(x2 * c + x1 * s);
}
__global__ __launch_bounds__(64) void rope_ck_kernel(const float* __restrict__ ck,
                                                     unsigned short* __restrict__ ckbf) {
  const int rh = blockIdx.x;
  const int r = rh / NHKV;
  const int t = threadIdx.x;
  const float* p = ck + (size_t)rh * DH;
  float x1 = p[t], x2 = p[t + 64];
  float inv = powf(10000.f, -(float)t / 64.f);
  float ang = (float)(r * CKST) * inv;
  float c, s;
  sincosf(ang, &s, &c);
  ckbf[(size_t)rh * DH + t]      = f2bf(x1 * c - x2 * s);
  ckbf[(size_t)rh * DH + t + 64] = f2bf(x2 * c + x1 * s);
}

// ---------------- MFMA compressed attention + pscore + top-k bitmask ----------------
constexpr int CSTR = 136;
__global__ __launch_bounds__(256) void cmp_attn_mfma(const unsigned short* __restrict__ qbf,
                                                     const unsigned short* __restrict__ ckbf,
                                                     const unsigned short* __restrict__ cvbf,
                                                     unsigned short* __restrict__ cmpobf,
                                                     unsigned* __restrict__ smask) {
  __shared__ __align__(16) unsigned short cks[64 * CSTR];
  __shared__ __align__(16) unsigned short cvts[128 * CSTR];
  __shared__ __align__(16) unsigned short Ps[4][16 * CSTR];
  __shared__ float pscore[16][132];
  const int h = blockIdx.x & 3;
  const int i0 = (blockIdx.x >> 2) * 16;
  const int t = threadIdx.x;
  const int w = t >> 6;
  const int lane = t & 63;
  const int col = lane & 15;
  const int quad = lane >> 4;
  const int iq = i0 + 4 * w + quad;

  short8 qf[4];
  {
    const int qi = i0 + 4 * w + (col >> 2);
    const int g = col & 3;
    const unsigned short* qp = qbf + ((size_t)qi * NHQ + h * GQ + g) * DH + quad * 8;
#pragma unroll
    for (int dc = 0; dc < 4; ++dc) qf[dc] = *(const short8*)(qp + dc * 32);
  }
  if (t < 64) pscore[t >> 2][128 + (t & 3)] = 0.f;
  const int jmax = (iq >= CKS - 1) ? ((iq - (CKS - 1)) >> 4) : -1;

  float sreg[8][4];
  for (int ch = 0; ch < 2; ++ch) {
    if (ch) __syncthreads();
    {
      const int r = t >> 2, c0 = (t & 3) * 32;
      const unsigned short* src = ckbf + ((size_t)(ch * 64 + r) * NHKV + h) * DH + c0;
#pragma unroll
      for (int u = 0; u < 4; ++u)
        *(short8*)&cks[r * CSTR + c0 + u * 8] = *(const short8*)(src + u * 8);
    }
    if (ch == 0) {
      const int j = t >> 1, d0 = (t & 1) * 64;
      const unsigned short* vsrc = cvbf + ((size_t)j * NHKV + h) * DH + d0;
#pragma unroll
      for (int u = 0; u < 16; ++u) {
        if (j == 127) {
#pragma unroll
          for (int dd = 0; dd < 4; ++dd) cvts[(d0 + u * 4 + dd) * CSTR + j] = 0;
        } else {
          us4 vv = *(const us4*)(vsrc + u * 4);
#pragma unroll
          for (int dd = 0; dd < 4; ++dd) cvts[(d0 + u * 4 + dd) * CSTR + j] = vv[dd];
        }
      }
    }
    __syncthreads();
#pragma unroll
    for (int tt = 0; tt < 4; ++tt) {
      f32x4 s = f32x4{0.f, 0.f, 0.f, 0.f};
#pragma unroll
      for (int dc = 0; dc < 4; ++dc)
        s = __builtin_amdgcn_mfma_f32_16x16x32_bf16(
            qf[dc], *(const short8*)&cks[(tt * 16 + col) * CSTR + dc * 32 + quad * 8], s, 0, 0, 0);
#pragma unroll
      for (int r = 0; r < 4; ++r) sreg[ch * 4 + tt][r] = s[r];
    }
  }

#pragma unroll
  for (int r = 0; r < 4; ++r) {
    float mx = -INFINITY;
#pragma unroll
    for (int tt = 0; tt < 8; ++tt) {
      const float val = (tt * 16 + col <= jmax) ? sreg[tt][r] * SCALE : -INFINITY;
      sreg[tt][r] = val;
      mx = fmaxf(mx, val);
    }
    mx = fmaxf(mx, __shfl_xor(mx, 1));
    mx = fmaxf(mx, __shfl_xor(mx, 2));
    mx = fmaxf(mx, __shfl_xor(mx, 4));
    mx = fmaxf(mx, __shfl_xor(mx, 8));
    float l = 0.f;
#pragma unroll
    for (int tt = 0; tt < 8; ++tt) {
      const float p = (sreg[tt][r] == -INFINITY) ? 0.f : __expf(sreg[tt][r] - mx);
      sreg[tt][r] = p;
      l += p;
    }
    l += __shfl_xor(l, 1); l += __shfl_xor(l, 2); l += __shfl_xor(l, 4); l += __shfl_xor(l, 8);
    const float rden = 1.f / fmaxf(l, 1e-20f);
#pragma unroll
    for (int tt = 0; tt < 8; ++tt) {
      const float pn = sreg[tt][r] * rden;
      sreg[tt][r] = pn;
      Ps[w][(quad * 4 + r) * CSTR + tt * 16 + col] = f2bf(pn);
    }
  }
#pragma unroll
  for (int tt = 0; tt < 8; ++tt)
    pscore[4 * w + quad][tt * 16 + col] = sreg[tt][0] + sreg[tt][1] + sreg[tt][2] + sreg[tt][3];

  f32x4 acc[8];
#pragma unroll
  for (int dt = 0; dt < 8; ++dt) acc[dt] = f32x4{0.f, 0.f, 0.f, 0.f};
#pragma unroll
  for (int kt = 0; kt < 4; ++kt) {
    short8 ap = *(const short8*)&Ps[w][col * CSTR + kt * 32 + quad * 8];
#pragma unroll
    for (int dt = 0; dt < 8; ++dt)
      acc[dt] = __builtin_amdgcn_mfma_f32_16x16x32_bf16(
          ap, *(const short8*)&cvts[(dt * 16 + col) * CSTR + kt * 32 + quad * 8], acc[dt], 0, 0, 0);
  }
#pragma unroll
  for (int dt = 0; dt < 8; ++dt)
#pragma unroll
    for (int r = 0; r < 4; ++r)
      cmpobf[((size_t)iq * NHQ + h * GQ + r) * DH + dt * 16 + col] = f2bf(acc[dt][r]);

  __syncthreads();
  if (t < 16) {
    const int i = i0 + t;
    const int qblk = i / BSZ;
    const float offw[5] = {1.f, 2.f, 2.f, 2.f, 1.f};
    float tmp[NBLK];
    for (int b = 0; b < NBLK; ++b) {
      float s = 0.f;
#pragma unroll
      for (int o = 0; o < 5; ++o) s += pscore[t][b * MBB + o] * offw[o];
      const bool causal = (b <= qblk);
      const bool forced = (b < 1) || ((b > qblk - 2) && causal);
      tmp[b] = causal ? (forced ? INFINITY : s) : -INFINITY;
    }
    unsigned msk = 0;
    for (int s = 0; s < NTOP; ++s) {
      int best = -1;
      float bv = -INFINITY;
      for (int b = 0; b < NBLK; ++b)
        if (tmp[b] > bv) { bv = tmp[b]; best = b; }
      if (best >= 0) { msk |= (1u << best); tmp[best] = -INFINITY; }
    }
    smask[(size_t)i * NHKV + h] = msk;
  }
}

// ---------------- dual-mask flash attention (selected + window), bf16 MFMA ----------------
constexpr int KSTR = 136;
constexpr int VSTR = 40;
constexpr int PSTR = 40;

__global__ __launch_bounds__(256) void nsa_attn_kernel(
    const unsigned short* __restrict__ qbf,
    const unsigned short* __restrict__ kbf,
    const unsigned short* __restrict__ vbf,
    const unsigned* __restrict__ smask,
    const float* __restrict__ gate,
    const unsigned short* __restrict__ cmpo,
    unsigned short* __restrict__ outc) {
  __shared__ __align__(16) unsigned short Ks[32 * KSTR];
  __shared__ __align__(16) unsigned short Vts[128 * VSTR];
  __shared__ __align__(16) unsigned short Ps[4][2][16 * PSTR];
  const int bx = blockIdx.x;
  const int h = bx >> 7;
  const int qt = 127 - (bx & 127);
  const int i0 = qt * 16;
  const int t = threadIdx.x;
  const int w = t >> 6;
  const int lane = t & 63;
  const int col = lane & 15;
  const int quad = lane >> 4;
  const int i0w = i0 + w * 4;
  const int i_lane = i0w + quad;

  short8 qf[4];
  {
    const int qi = i0w + (col >> 2);
    const int g = col & 3;
    const unsigned short* qp = qbf + (((size_t)qi * NHQ) + h * 4 + g) * DH + quad * 8;
#pragma unroll
    for (int dc = 0; dc < 4; ++dc) qf[dc] = *(const short8*)(qp + dc * 32);
  }
  const unsigned mymask = smask[(size_t)i_lane * NHKV + h];

  f32x4 accS[8], accW[8];
#pragma unroll
  for (int dt = 0; dt < 8; ++dt) { accS[dt] = f32x4{0.f,0.f,0.f,0.f}; accW[dt] = f32x4{0.f,0.f,0.f,0.f}; }
  float mS[4], mW[4], lS[4], lW[4];
#pragma unroll
  for (int r = 0; r < 4; ++r) { mS[r] = -INFINITY; mW[r] = -INFINITY; lS[r] = 0.f; lW[r] = 0.f; }

  const int ntile = (i0 + 16 + 31) >> 5;
  for (int tile = 0; tile < ntile; ++tile) {
    const int j0 = tile * 32;
    {
      const int r = t >> 3, c = (t & 7) * 16;
      const unsigned short* src = kbf + ((size_t)((j0 + r) * NHKV + h)) * DH + c;
      *(short8*)(&Ks[r * KSTR + c])     = *(const short8*)(src);
      *(short8*)(&Ks[r * KSTR + c + 8]) = *(const short8*)(src + 8);
    }
#pragma unroll
    for (int rep = 0; rep < 4; ++rep) {
      const int u = rep * 256 + t;
      const int j = u & 31, dg = u >> 5;
      us4 vv = *(const us4*)(vbf + ((size_t)((j0 + j) * NHKV + h)) * DH + dg * 4);
#pragma unroll
      for (int dd = 0; dd < 4; ++dd) Vts[(dg * 4 + dd) * VSTR + j] = vv[dd];
    }
    __syncthreads();

    const bool anywork = (j0 <= i0w + 3);
    const int blk = j0 >> 6;
    const bool selbit = anywork && ((mymask >> blk) & 1u);
    const bool selAny = (__ballot(selbit) != 0ull);
    const bool winAny = anywork && (j0 + 31 >= i0w - WINW);

    if (selAny || winAny) {
      f32x4 s0 = f32x4{0.f,0.f,0.f,0.f}, s1 = f32x4{0.f,0.f,0.f,0.f};
#pragma unroll
      for (int dc = 0; dc < 4; ++dc) {
        short8 kf0 = *(const short8*)(&Ks[(col)      * KSTR + dc * 32 + quad * 8]);
        short8 kf1 = *(const short8*)(&Ks[(16 + col) * KSTR + dc * 32 + quad * 8]);
        s0 = __builtin_amdgcn_mfma_f32_16x16x32_bf16(qf[dc], kf0, s0, 0, 0, 0);
        s1 = __builtin_amdgcn_mfma_f32_16x16x32_bf16(qf[dc], kf1, s1, 0, 0, 0);
      }
      const int jA = j0 + col, jB = j0 + 16 + col;
      const bool cA = (jA <= i_lane), cB = (jB <= i_lane);

      auto dobranch = [&](bool bA, bool bB, float* mrun, float* lrun,
                          f32x4* acc, unsigned short* P) {
#pragma unroll
        for (int r = 0; r < 4; ++r) {
          float vA = bA ? s0[r] * SCALE : -INFINITY;
          float vB = bB ? s1[r] * SCALE : -INFINITY;
          float tm = fmaxf(vA, vB);
          tm = fmaxf(tm, __shfl_xor(tm, 1));
          tm = fmaxf(tm, __shfl_xor(tm, 2));
          tm = fmaxf(tm, __shfl_xor(tm, 4));
          tm = fmaxf(tm, __shfl_xor(tm, 8));
          float mn = fmaxf(mrun[r], tm);
          float a = (mn == -INFINITY) ? 1.f : __expf(mrun[r] - mn);
          float pA = bA ? __expf(vA - mn) : 0.f;
          float pB = bB ? __expf(vB - mn) : 0.f;
          lrun[r] = lrun[r] * a + pA + pB;
          mrun[r] = mn;
#pragma unroll
          for (int dt = 0; dt < 8; ++dt) acc[dt][r] *= a;
          P[(quad * 4 + r) * PSTR + col]      = f2bf(pA);
          P[(quad * 4 + r) * PSTR + 16 + col] = f2bf(pB);
        }
      };
      if (selAny) dobranch(selbit && cA, selbit && cB, mS, lS, accS, &Ps[w][0][0]);
      if (winAny) dobranch(cA && (jA >= i_lane - WINW), cB && (jB >= i_lane - WINW),
                           mW, lW, accW, &Ps[w][1][0]);

      short8 vf[8];
#pragma unroll
      for (int dt = 0; dt < 8; ++dt)
        vf[dt] = *(const short8*)(&Vts[(dt * 16 + col) * VSTR + quad * 8]);
      if (selAny) {
        short8 ap = *(const short8*)(&Ps[w][0][col * PSTR + quad * 8]);
#pragma unroll
        for (int dt = 0; dt < 8; ++dt)
          accS[dt] = __builtin_amdgcn_mfma_f32_16x16x32_bf16(ap, vf[dt], accS[dt], 0, 0, 0);
      }
      if (winAny) {
        short8 ap = *(const short8*)(&Ps[w][1][col * PSTR + quad * 8]);
#pragma unroll
        for (int dt = 0; dt < 8; ++dt)
          accW[dt] = __builtin_amdgcn_mfma_f32_16x16x32_bf16(ap, vf[dt], accW[dt], 0, 0, 0);
      }
    }
    __syncthreads();
  }

#pragma unroll
  for (int r = 0; r < 4; ++r) {
    float v = lS[r];
    v += __shfl_xor(v, 1); v += __shfl_xor(v, 2); v += __shfl_xor(v, 4); v += __shfl_xor(v, 8);
    lS[r] = v;
    float u = lW[r];
    u += __shfl_xor(u, 1); u += __shfl_xor(u, 2); u += __shfl_xor(u, 4); u += __shfl_xor(u, 8);
    lW[r] = u;
  }
  const float g0 = gate[i_lane * 3 + 0];
  const float g1 = gate[i_lane * 3 + 1];
  const float g2 = gate[i_lane * 3 + 2];
#pragma unroll
  for (int r = 0; r < 4; ++r) {
    const size_t base = ((size_t)i_lane * NHQ + h * 4 + r) * DH;
    const float rls = g1 / lS[r];
    const float rlw = g2 / lW[r];
#pragma unroll
    for (int dt = 0; dt < 8; ++dt) {
      const size_t o = base + dt * 16 + col;
      outc[o] = f2bf(g0 * bf2f(cmpo[o]) + rls * accS[dt][r] + rlw * accW[dt][r]);
    }
  }
}

// ---------------- launcher ----------------
extern "C" void kernel_launch(void* const* d_in, const int* in_sizes, int n_in,
                              void* d_out, int out_size, void* d_ws, size_t ws_size,
                              hipStream_t stream) {
  const float* x   = (const float*)d_in[0];
  const float* Wq  = (const float*)d_in[2];
  const float* Wk  = (const float*)d_in[3];
  const float* Wv  = (const float*)d_in[4];
  const float* Wo  = (const float*)d_in[5];
  const float* Wck = (const float*)d_in[6];
  const float* Wcv = (const float*)d_in[7];
  const float* pe  = (const float*)d_in[8];
  const float* Wg  = (const float*)d_in[9];
  float* out = (float*)d_out;

  unsigned char* p = (unsigned char*)d_ws;
  auto alloc = [&](size_t bytes) { void* r = p; p += (bytes + 255) & ~(size_t)255; return r; };
  float* q    = (float*)alloc((size_t)SEQ * NHQ * DH * 4);    // 16MB; dead after rope_q -> WoT
  float* kbuf = (float*)alloc((size_t)SEQ * NHKV * DH * 4);   // 4MB; kbuf+vbuf -> combbf
  float* vbuf = (float*)alloc((size_t)SEQ * NHKV * DH * 4);   // 4MB
  float* ck   = (float*)alloc((size_t)128 * NHKV * DH * 4);   // 256KB
  float* gbuf = (float*)alloc((size_t)SEQ * 4 * 4);
  unsigned* smask = (unsigned*)alloc((size_t)SEQ * NHKV * 4);
  unsigned short* ckbf = (unsigned short*)alloc((size_t)128 * NHKV * DH * 2);
  unsigned short* cvbf = (unsigned short*)alloc((size_t)128 * NHKV * DH * 2);
  unsigned short* xbf  = (unsigned short*)alloc((size_t)SEQ * HID * 2);       // 8MB; -> Ak/Av -> cmpobf
  unsigned short* WqT  = (unsigned short*)alloc((size_t)NHQ * DH * HID * 2);  // 8MB; -> qbf
  unsigned short* WkT  = (unsigned short*)alloc((size_t)NHKV * DH * HID * 2); // 2MB; -> krbf
  unsigned short* WvT  = (unsigned short*)alloc((size_t)NHKV * DH * HID * 2); // 2MB; -> vbf
  unsigned short* WckT = (unsigned short*)alloc((size_t)NHKV * DH * CKD * 2); // 4MB
  unsigned short* WcvT = (unsigned short*)alloc((size_t)NHKV * DH * CKD * 2); // 4MB
  float* Cpart = (float*)alloc((size_t)32 * 128 * 128 * 4);                   // 2MB
  unsigned short* WoT    = (unsigned short*)q;
  unsigned short* combbf = (unsigned short*)kbuf;   // kbuf+vbuf = 8MB contiguous
  unsigned short* Ak     = xbf;                     // Ak+Av = 8MB = xbf region
  unsigned short* Av     = xbf + (size_t)NHKV * 128 * CKD;
  unsigned short* cmpobf = xbf;
  unsigned short* qbf  = WqT;
  unsigned short* krbf = WkT;
  unsigned short* vbf  = WvT;

  // convert / transpose
  conv_bf_kernel<<<(SEQ * HID) / 256, 256, 0, stream>>>(x, xbf);
  transpose_bf_kernel<<<dim3((NHQ * DH) / 32, HID / 32), dim3(32, 8), 0, stream>>>(Wq, WqT, HID, NHQ * DH);
  transpose_bf_kernel<<<dim3((NHKV * DH) / 32, HID / 32), dim3(32, 8), 0, stream>>>(Wk, WkT, HID, NHKV * DH);
  transpose_bf_kernel<<<dim3((NHKV * DH) / 32, HID / 32), dim3(32, 8), 0, stream>>>(Wv, WvT, HID, NHKV * DH);
  transpose_bf_kernel<<<dim3(DH / 32, CKD / 32, NHKV), dim3(32, 8), 0, stream>>>(Wck, WckT, CKD, DH);
  transpose_bf_kernel<<<dim3(DH / 32, CKD / 32, NHKV), dim3(32, 8), 0, stream>>>(Wcv, WcvT, CKD, DH);
  // projections (bf16 MFMA, 128x128 tiles)
  gemm_bf16_128<<<dim3((NHQ * DH) / 128, SEQ / 128), 256, 0, stream>>>(xbf, WqT, q, SEQ, NHQ * DH, HID);
  gemm_bf16_128<<<dim3((NHKV * DH) / 128, SEQ / 128), 256, 0, stream>>>(xbf, WkT, kbuf, SEQ, NHKV * DH, HID);
  gemm_bf16_128<<<dim3((NHKV * DH) / 128, SEQ / 128), 256, 0, stream>>>(xbf, WvT, vbuf, SEQ, NHKV * DH, HID);
  gate_kernel<<<SEQ, 128, 0, stream>>>(x, Wg, gbuf);
  // compression as GEMM (A-build overwrites dead xbf)
  abuild_kernel<<<(NHKV * 128 * CKD) / 256, 256, 0, stream>>>(kbuf, vbuf, pe, Ak, Av);
  compress_gemm<<<32, 256, 0, stream>>>(Ak, Av, WckT, WcvT, Cpart);
  compress_reduce<<<(2 * NHKV * 128 * DH) / 256, 256, 0, stream>>>(Cpart, ck, cvbf);
  // RoPE + conversions
  rope_q_kernel<<<SEQ * NHQ, 64, 0, stream>>>(q, qbf);
  transpose_bf_kernel<<<dim3(HID / 32, (NHQ * DH) / 32), dim3(32, 8), 0, stream>>>(Wo, WoT, NHQ * DH, HID);
  rope_k_kernel<<<SEQ * NHKV, 64, 0, stream>>>(kbuf, krbf);
  rope_ck_kernel<<<NCMP * NHKV, 64, 0, stream>>>(ck, ckbf);
  conv_bf_kernel<<<(SEQ * NHKV * DH) / 256, 256, 0, stream>>>(vbuf, vbf);
  // compressed attention + selection (cmpobf overwrites dead Ak/Av)
  cmp_attn_mfma<<<(SEQ / 16) * NHKV, 256, 0, stream>>>(qbf, ckbf, cvbf, cmpobf, smask);
  // selected + window attention + gated combine
  nsa_attn_kernel<<<(SEQ / 16) * NHKV, 256, 0, stream>>>(qbf, krbf, vbf, smask, gbuf, cmpobf, combbf);
  // output projection
  gemm_bf16_128<<<dim3(HID / 128, SEQ / 128), 256, 0, stream>>>(combbf, WoT, out, SEQ, HID, NHQ * DH);
}

// Round 5
// 455.420 us; speedup vs baseline: 11.3902x; 1.3567x over previous
//
#include <hip/hip_runtime.h>
#include <math.h>

// ---------------- problem constants ----------------
constexpr int SEQ   = 2048;   // L
constexpr int HID   = 2048;
constexpr int NHQ   = 16;
constexpr int NHKV  = 4;
constexpr int GQ    = NHQ / NHKV;   // 4
constexpr int DH    = 128;
constexpr int CKS   = 32;     // compress window
constexpr int CKST  = 16;     // compress stride
constexpr int NCMP  = (SEQ - CKS) / CKST + 1;  // 127
constexpr int BSZ   = 64;     // selection block
constexpr int NTOP  = 16;
constexpr int NBLK  = SEQ / BSZ;   // 32
constexpr int MBB   = BSZ / CKST;  // 4
constexpr int WINW  = 512;
constexpr int CKD   = CKS * DH;    // 4096 = compress GEMM K
constexpr int NQKV  = HID + 2 * NHKV * DH;  // 3072 fused projection width
constexpr float SCALE = 0.08838834764831845f;  // 1/sqrt(128)

typedef __attribute__((ext_vector_type(8))) short short8;     // 8 bf16 (4 VGPRs)
typedef __attribute__((ext_vector_type(4))) float f32x4;

static __device__ __forceinline__ unsigned short f2bf(float f) {
  unsigned u = __builtin_bit_cast(unsigned, f);
  u = (u + 0x7fffu + ((u >> 16) & 1u)) >> 16;
  return (unsigned short)u;
}
static __device__ __forceinline__ float bf2f(unsigned short u) {
  unsigned v = ((unsigned)u) << 16;
  return __builtin_bit_cast(float, v);
}
// async global->LDS 16B: lane i writes lds_base + i*16
static __device__ __forceinline__ void gload_lds16(const unsigned short* g, unsigned short* l) {
  __builtin_amdgcn_global_load_lds((const __attribute__((address_space(1))) unsigned int*)g,
                                   (__attribute__((address_space(3))) unsigned int*)l, 16, 0, 0);
}

// ---------------- fp32 -> bf16 flat convert ----------------
__global__ __launch_bounds__(256) void conv_bf_kernel(const float* __restrict__ in,
                                                      unsigned short* __restrict__ out) {
  const size_t u = (size_t)blockIdx.x * 256 + threadIdx.x;
  out[u] = f2bf(in[u]);
}

// ---------------- fp32 [K][N] -> bf16 [N][K] tiled transpose (batched over z) ----------------
__global__ __launch_bounds__(256) void transpose_bf_kernel(const float* __restrict__ in,
                                                           unsigned short* __restrict__ out,
                                                           int K, int N) {
  __shared__ float tile[32][33];
  const int tx = threadIdx.x, ty = threadIdx.y;  // 32 x 8
  const int n0 = blockIdx.x * 32, k0 = blockIdx.y * 32;
  const size_t zo = (size_t)blockIdx.z * K * N;
  const float* inz = in + zo;
  unsigned short* outz = out + zo;
#pragma unroll
  for (int r = 0; r < 4; ++r)
    tile[ty + 8 * r][tx] = inz[(size_t)(k0 + ty + 8 * r) * N + n0 + tx];
  __syncthreads();
#pragma unroll
  for (int r = 0; r < 4; ++r)
    outz[(size_t)(n0 + ty + 8 * r) * K + k0 + tx] = f2bf(tile[tx][ty + 8 * r]);
}

// ---------------- bf16 MFMA GEMM, 128x128 tile ----------------
__global__ __launch_bounds__(256) void gemm_bf16_128(const unsigned short* __restrict__ A,
                                                     const unsigned short* __restrict__ Bt,
                                                     float* __restrict__ C,
                                                     int M, int N, int K) {
  __shared__ __align__(16) unsigned short As[128 * 40];
  __shared__ __align__(16) unsigned short Bs[128 * 40];
  const int t = threadIdx.x;
  const int w = t >> 6;
  const int lane = t & 63;
  const int col = lane & 15;
  const int quad = lane >> 4;
  const int m0 = blockIdx.y * 128, n0 = blockIdx.x * 128;
  const int ra = t >> 1, ha = (t & 1) * 16;
  f32x4 acc[2][8];
#pragma unroll
  for (int mi = 0; mi < 2; ++mi)
#pragma unroll
    for (int ni = 0; ni < 8; ++ni) acc[mi][ni] = f32x4{0.f, 0.f, 0.f, 0.f};

  for (int k0 = 0; k0 < K; k0 += 32) {
    const unsigned short* sA = A + (size_t)(m0 + ra) * K + k0 + ha;
    *(short8*)&As[ra * 40 + ha]     = *(const short8*)sA;
    *(short8*)&As[ra * 40 + ha + 8] = *(const short8*)(sA + 8);
    const unsigned short* sB = Bt + (size_t)(n0 + ra) * K + k0 + ha;
    *(short8*)&Bs[ra * 40 + ha]     = *(const short8*)sB;
    *(short8*)&Bs[ra * 40 + ha + 8] = *(const short8*)(sB + 8);
    __syncthreads();
    short8 af[2], bfr[8];
#pragma unroll
    for (int mi = 0; mi < 2; ++mi)
      af[mi] = *(const short8*)&As[(w * 32 + mi * 16 + col) * 40 + quad * 8];
#pragma unroll
    for (int ni = 0; ni < 8; ++ni)
      bfr[ni] = *(const short8*)&Bs[(ni * 16 + col) * 40 + quad * 8];
#pragma unroll
    for (int mi = 0; mi < 2; ++mi)
#pragma unroll
      for (int ni = 0; ni < 8; ++ni)
        acc[mi][ni] = __builtin_amdgcn_mfma_f32_16x16x32_bf16(af[mi], bfr[ni], acc[mi][ni], 0, 0, 0);
    __syncthreads();
  }
#pragma unroll
  for (int mi = 0; mi < 2; ++mi)
#pragma unroll
    for (int ni = 0; ni < 8; ++ni)
#pragma unroll
      for (int r = 0; r < 4; ++r)
        C[(size_t)(m0 + w * 32 + mi * 16 + quad * 4 + r) * N + n0 + ni * 16 + col] = acc[mi][ni][r];
}

// ---------------- compress A-build from fused qkv: Ak/Av[h][128][4096] bf16 ----------------
__global__ __launch_bounds__(256) void abuild_kernel(const float* __restrict__ qkv,
                                                     const float* __restrict__ pe,
                                                     unsigned short* __restrict__ Ak,
                                                     unsigned short* __restrict__ Av) {
  const size_t u = (size_t)blockIdx.x * 256 + threadIdx.x;  // < 4*128*4096
  const int h = (int)(u >> 19);
  const int rem = (int)(u & 524287);
  const int n = rem >> 12;
  const int e = rem & 4095;
  const int s = e >> 7;
  const int d = e & 127;
  int row = n * CKST + s; if (row > SEQ - 1) row = SEQ - 1;  // pad row (n=127 unused)
  const float* base = qkv + (size_t)row * NQKV + h * DH + d;
  Ak[u] = f2bf(base[HID] + pe[((size_t)h * CKS + s) * DH + d]);
  Av[u] = f2bf(base[HID + NHKV * DH]);
}

// ---------------- compress GEMM (split-K partials): z = mat*16 + h*4 + kc ----------------
__global__ __launch_bounds__(256) void compress_gemm(const unsigned short* __restrict__ Ak,
                                                     const unsigned short* __restrict__ Av,
                                                     const unsigned short* __restrict__ WckT,
                                                     const unsigned short* __restrict__ WcvT,
                                                     float* __restrict__ Cpart) {
  __shared__ __align__(16) unsigned short As[128 * 40];
  __shared__ __align__(16) unsigned short Bs[128 * 40];
  const int z = blockIdx.x;
  const int mat = z >> 4;
  const int h = (z >> 2) & 3;
  const int kc = z & 3;
  const unsigned short* A  = (mat ? Av : Ak)     + (size_t)h * 128 * CKD;
  const unsigned short* Bt = (mat ? WcvT : WckT) + (size_t)h * DH * CKD;
  float* Cout = Cpart + (size_t)z * 128 * 128;
  const int t = threadIdx.x;
  const int w = t >> 6;
  const int lane = t & 63;
  const int col = lane & 15;
  const int quad = lane >> 4;
  const int ra = t >> 1, ha = (t & 1) * 16;
  f32x4 acc[2][8];
#pragma unroll
  for (int mi = 0; mi < 2; ++mi)
#pragma unroll
    for (int ni = 0; ni < 8; ++ni) acc[mi][ni] = f32x4{0.f, 0.f, 0.f, 0.f};
  for (int k0 = kc * 1024; k0 < kc * 1024 + 1024; k0 += 32) {
    const unsigned short* sA = A + (size_t)ra * CKD + k0 + ha;
    *(short8*)&As[ra * 40 + ha]     = *(const short8*)sA;
    *(short8*)&As[ra * 40 + ha + 8] = *(const short8*)(sA + 8);
    const unsigned short* sB = Bt + (size_t)ra * CKD + k0 + ha;
    *(short8*)&Bs[ra * 40 + ha]     = *(const short8*)sB;
    *(short8*)&Bs[ra * 40 + ha + 8] = *(const short8*)(sB + 8);
    __syncthreads();
    short8 af[2], bfr[8];
#pragma unroll
    for (int mi = 0; mi < 2; ++mi)
      af[mi] = *(const short8*)&As[(w * 32 + mi * 16 + col) * 40 + quad * 8];
#pragma unroll
    for (int ni = 0; ni < 8; ++ni)
      bfr[ni] = *(const short8*)&Bs[(ni * 16 + col) * 40 + quad * 8];
#pragma unroll
    for (int mi = 0; mi < 2; ++mi)
#pragma unroll
      for (int ni = 0; ni < 8; ++ni)
        acc[mi][ni] = __builtin_amdgcn_mfma_f32_16x16x32_bf16(af[mi], bfr[ni], acc[mi][ni], 0, 0, 0);
    __syncthreads();
  }
#pragma unroll
  for (int mi = 0; mi < 2; ++mi)
#pragma unroll
    for (int ni = 0; ni < 8; ++ni)
#pragma unroll
      for (int r = 0; r < 4; ++r)
        Cout[(size_t)(w * 32 + mi * 16 + quad * 4 + r) * 128 + ni * 16 + col] = acc[mi][ni][r];
}

// ---------------- compress reduce + fused ck-RoPE -> ckbf / cvbf ----------------
__global__ __launch_bounds__(256) void compress_reduce_rope(const float* __restrict__ Cpart,
                                                            unsigned short* __restrict__ ckbf,
                                                            unsigned short* __restrict__ cvbf) {
  const unsigned u = blockIdx.x * 256 + threadIdx.x;  // < 32768 + 65536
  if (u < 32768) {  // ck with rope: (h, n, d<64)
    const int h = u >> 13;
    const int rem = u & 8191;
    const int n = rem >> 6;
    const int d = rem & 63;
    const size_t b0 = ((size_t)(h * 4) << 14) + n * 128 + d;
    float x1 = Cpart[b0] + Cpart[b0 + 16384] + Cpart[b0 + 2 * 16384] + Cpart[b0 + 3 * 16384];
    float x2 = Cpart[b0 + 64] + Cpart[b0 + 64 + 16384] + Cpart[b0 + 64 + 2 * 16384] + Cpart[b0 + 64 + 3 * 16384];
    float inv = powf(10000.f, -(float)d / 64.f);
    float ang = (float)(n * CKST) * inv;
    float c, s;
    sincosf(ang, &s, &c);
    const size_t o = ((size_t)n * NHKV + h) * DH + d;
    ckbf[o]      = f2bf(x1 * c - x2 * s);
    ckbf[o + 64] = f2bf(x2 * c + x1 * s);
  } else {  // cv: (h, n, d)
    const unsigned u2 = u - 32768;
    const int h = u2 >> 14;
    const int rem = u2 & 16383;
    const size_t b0 = ((size_t)(16 + h * 4) << 14) + rem;
    float s = Cpart[b0] + Cpart[b0 + 16384] + Cpart[b0 + 2 * 16384] + Cpart[b0 + 3 * 16384];
    const int n = rem >> 7, d = rem & 127;
    cvbf[((size_t)n * NHKV + h) * DH + d] = f2bf(s);
  }
}

// ---------------- gate = sigmoid(x @ Wg) ----------------
__global__ __launch_bounds__(128) void gate_kernel(const float* __restrict__ x,
                                                   const float* __restrict__ Wg,
                                                   float* __restrict__ gate) {
  const int i = blockIdx.x;
  const int t = threadIdx.x;
  float a0 = 0.f, a1 = 0.f, a2 = 0.f;
  for (int kk = t; kk < HID; kk += 128) {
    float xv = x[(size_t)i * HID + kk];
    a0 += xv * Wg[kk * 3 + 0];
    a1 += xv * Wg[kk * 3 + 1];
    a2 += xv * Wg[kk * 3 + 2];
  }
#pragma unroll
  for (int s = 1; s < 64; s <<= 1) {
    a0 += __shfl_xor(a0, s);
    a1 += __shfl_xor(a1, s);
    a2 += __shfl_xor(a2, s);
  }
  __shared__ float part[2][3];
  if ((t & 63) == 0) { part[t >> 6][0] = a0; part[t >> 6][1] = a1; part[t >> 6][2] = a2; }
  __syncthreads();
  if (t == 0) {
    gate[i * 3 + 0] = 1.f / (1.f + expf(-(part[0][0] + part[1][0])));
    gate[i * 3 + 1] = 1.f / (1.f + expf(-(part[0][1] + part[1][1])));
    gate[i * 3 + 2] = 1.f / (1.f + expf(-(part[0][2] + part[1][2])));
  }
}

// ---------------- RoPE (reads fused qkv, stride NQKV) ----------------
__global__ __launch_bounds__(64) void rope_q_kernel(const float* __restrict__ qkv,
                                                    unsigned short* __restrict__ qbf) {
  const int rh = blockIdx.x;
  const int r = rh >> 4;
  const int hq = rh & 15;
  const int t = threadIdx.x;
  const float* p = qkv + (size_t)r * NQKV + hq * DH;
  float x1 = p[t], x2 = p[t + 64];
  float inv = powf(10000.f, -(float)t / 64.f);
  float ang = (float)r * inv;
  float c, s;
  sincosf(ang, &s, &c);
  qbf[(size_t)rh * DH + t]      = f2bf(x1 * c - x2 * s);
  qbf[(size_t)rh * DH + t + 64] = f2bf(x2 * c + x1 * s);
}
__global__ __launch_bounds__(64) void rope_k_kernel(const float* __restrict__ qkv,
                                                    unsigned short* __restrict__ kbf) {
  const int rh = blockIdx.x;
  const int r = rh >> 2;
  const int h = rh & 3;
  const int t = threadIdx.x;
  const float* p = qkv + (size_t)r * NQKV + HID + h * DH;
  float x1 = p[t], x2 = p[t + 64];
  float inv = powf(10000.f, -(float)t / 64.f);
  float ang = (float)r * inv;
  float c, s;
  sincosf(ang, &s, &c);
  kbf[(size_t)rh * DH + t]      = f2bf(x1 * c - x2 * s);
  kbf[(size_t)rh * DH + t + 64] = f2bf(x2 * c + x1 * s);
}
// ---------------- V transpose: qkv v-part [i][h*128+d] -> vT[h][d][i] bf16 ----------------
__global__ __launch_bounds__(256) void vtrans_kernel(const float* __restrict__ qkv,
                                                     unsigned short* __restrict__ vT) {
  __shared__ float tile[32][33];
  const int tx = threadIdx.x, ty = threadIdx.y;  // 32 x 8
  const int ix = blockIdx.x * 32;   // seq
  const int dx = blockIdx.y * 32;   // d
  const int h = blockIdx.z;
#pragma unroll
  for (int r = 0; r < 4; ++r)
    tile[ty + 8 * r][tx] = qkv[(size_t)(ix + ty + 8 * r) * NQKV + HID + NHKV * DH + h * DH + dx + tx];
  __syncthreads();
#pragma unroll
  for (int r = 0; r < 4; ++r)
    vT[(size_t)(h * DH + dx + ty + 8 * r) * SEQ + ix + tx] = f2bf(tile[tx][ty + 8 * r]);
}

// ---------------- MFMA compressed attention + pscore + top-k bitmask ----------------
constexpr int CSTR = 136;
__global__ __launch_bounds__(256) void cmp_attn_mfma(const unsigned short* __restrict__ qbf,
                                                     const unsigned short* __restrict__ ckbf,
                                                     const unsigned short* __restrict__ cvbf,
                                                     unsigned short* __restrict__ cmpobf,
                                                     unsigned* __restrict__ smask) {
  __shared__ __align__(16) unsigned short cks[64 * CSTR];
  __shared__ __align__(16) unsigned short cvts[128 * CSTR];
  __shared__ __align__(16) unsigned short Ps[4][16 * CSTR];
  __shared__ float pscore[16][132];
  const int h = blockIdx.x & 3;
  const int i0 = (blockIdx.x >> 2) * 16;
  const int t = threadIdx.x;
  const int w = t >> 6;
  const int lane = t & 63;
  const int col = lane & 15;
  const int quad = lane >> 4;
  const int iq = i0 + 4 * w + quad;

  short8 qf[4];
  {
    const int qi = i0 + 4 * w + (col >> 2);
    const int g = col & 3;
    const unsigned short* qp = qbf + ((size_t)qi * NHQ + h * GQ + g) * DH + quad * 8;
#pragma unroll
    for (int dc = 0; dc < 4; ++dc) qf[dc] = *(const short8*)(qp + dc * 32);
  }
  if (t < 64) pscore[t >> 2][128 + (t & 3)] = 0.f;
  const int jmax = (iq >= CKS - 1) ? ((iq - (CKS - 1)) >> 4) : -1;

  float sreg[8][4];
  for (int ch = 0; ch < 2; ++ch) {
    if (ch) __syncthreads();
    {
      const int r = t >> 2, c0 = (t & 3) * 32;
      const unsigned short* src = ckbf + ((size_t)(ch * 64 + r) * NHKV + h) * DH + c0;
#pragma unroll
      for (int u = 0; u < 4; ++u)
        *(short8*)&cks[r * CSTR + c0 + u * 8] = *(const short8*)(src + u * 8);
    }
    if (ch == 0) {
      const int j = t >> 1, d0 = (t & 1) * 64;
      const unsigned short* vsrc = cvbf + ((size_t)j * NHKV + h) * DH + d0;
#pragma unroll
      for (int u = 0; u < 16; ++u) {
        if (j == 127) {
#pragma unroll
          for (int dd = 0; dd < 4; ++dd) cvts[(d0 + u * 4 + dd) * CSTR + j] = 0;
        } else {
          const unsigned short* vv = vsrc + u * 4;
#pragma unroll
          for (int dd = 0; dd < 4; ++dd) cvts[(d0 + u * 4 + dd) * CSTR + j] = vv[dd];
        }
      }
    }
    __syncthreads();
#pragma unroll
    for (int tt = 0; tt < 4; ++tt) {
      f32x4 s = f32x4{0.f, 0.f, 0.f, 0.f};
#pragma unroll
      for (int dc = 0; dc < 4; ++dc)
        s = __builtin_amdgcn_mfma_f32_16x16x32_bf16(
            qf[dc], *(const short8*)&cks[(tt * 16 + col) * CSTR + dc * 32 + quad * 8], s, 0, 0, 0);
#pragma unroll
      for (int r = 0; r < 4; ++r) sreg[ch * 4 + tt][r] = s[r];
    }
  }

#pragma unroll
  for (int r = 0; r < 4; ++r) {
    float mx = -INFINITY;
#pragma unroll
    for (int tt = 0; tt < 8; ++tt) {
      const float val = (tt * 16 + col <= jmax) ? sreg[tt][r] * SCALE : -INFINITY;
      sreg[tt][r] = val;
      mx = fmaxf(mx, val);
    }
    mx = fmaxf(mx, __shfl_xor(mx, 1));
    mx = fmaxf(mx, __shfl_xor(mx, 2));
    mx = fmaxf(mx, __shfl_xor(mx, 4));
    mx = fmaxf(mx, __shfl_xor(mx, 8));
    float l = 0.f;
#pragma unroll
    for (int tt = 0; tt < 8; ++tt) {
      const float p = (sreg[tt][r] == -INFINITY) ? 0.f : __expf(sreg[tt][r] - mx);
      sreg[tt][r] = p;
      l += p;
    }
    l += __shfl_xor(l, 1); l += __shfl_xor(l, 2); l += __shfl_xor(l, 4); l += __shfl_xor(l, 8);
    const float rden = 1.f / fmaxf(l, 1e-20f);
#pragma unroll
    for (int tt = 0; tt < 8; ++tt) {
      const float pn = sreg[tt][r] * rden;
      sreg[tt][r] = pn;
      Ps[w][(quad * 4 + r) * CSTR + tt * 16 + col] = f2bf(pn);
    }
  }
#pragma unroll
  for (int tt = 0; tt < 8; ++tt)
    pscore[4 * w + quad][tt * 16 + col] = sreg[tt][0] + sreg[tt][1] + sreg[tt][2] + sreg[tt][3];

  f32x4 acc[8];
#pragma unroll
  for (int dt = 0; dt < 8; ++dt) acc[dt] = f32x4{0.f, 0.f, 0.f, 0.f};
#pragma unroll
  for (int kt = 0; kt < 4; ++kt) {
    short8 ap = *(const short8*)&Ps[w][col * CSTR + kt * 32 + quad * 8];
#pragma unroll
    for (int dt = 0; dt < 8; ++dt)
      acc[dt] = __builtin_amdgcn_mfma_f32_16x16x32_bf16(
          ap, *(const short8*)&cvts[(dt * 16 + col) * CSTR + kt * 32 + quad * 8], acc[dt], 0, 0, 0);
  }
#pragma unroll
  for (int dt = 0; dt < 8; ++dt)
#pragma unroll
    for (int r = 0; r < 4; ++r)
      cmpobf[((size_t)iq * NHQ + h * GQ + r) * DH + dt * 16 + col] = f2bf(acc[dt][r]);

  __syncthreads();
  if (t < 16) {
    const int i = i0 + t;
    const int qblk = i / BSZ;
    const float offw[5] = {1.f, 2.f, 2.f, 2.f, 1.f};
    float tmp[NBLK];
    for (int b = 0; b < NBLK; ++b) {
      float s = 0.f;
#pragma unroll
      for (int o = 0; o < 5; ++o) s += pscore[t][b * MBB + o] * offw[o];
      const bool causal = (b <= qblk);
      const bool forced = (b < 1) || ((b > qblk - 2) && causal);
      tmp[b] = causal ? (forced ? INFINITY : s) : -INFINITY;
    }
    unsigned msk = 0;
    for (int s = 0; s < NTOP; ++s) {
      int best = -1;
      float bv = -INFINITY;
      for (int b = 0; b < NBLK; ++b)
        if (tmp[b] > bv) { bv = tmp[b]; best = b; }
      if (best >= 0) { msk |= (1u << best); tmp[best] = -INFINITY; }
    }
    smask[(size_t)i * NHKV + h] = msk;
  }
}

// ---------------- dual-mask flash attention: 64-key tiles, async staging, swizzled LDS ----------
__global__ __launch_bounds__(256) void nsa_attn_kernel(
    const unsigned short* __restrict__ qbf,
    const unsigned short* __restrict__ kbf,
    const unsigned short* __restrict__ vT,
    const unsigned* __restrict__ smask,
    const float* __restrict__ gate,
    const unsigned short* __restrict__ cmpo,
    unsigned short* __restrict__ outc) {
  __shared__ __align__(16) unsigned short Ks[2][64 * 128];  // 32 KB, double-buffered
  __shared__ __align__(16) unsigned short Vs[128 * 64];     // 16 KB
  __shared__ __align__(16) unsigned short Ps[4][16 * 64];   // 8 KB (per-wave P)
  const int bx = blockIdx.x;
  const int qt = 127 - (bx >> 2);   // big-work blocks first
  const int h = bx & 3;
  const int i0 = qt * 16;
  const int t = threadIdx.x;
  const int w = t >> 6;
  const int lane = t & 63;
  const int col = lane & 15;
  const int quad = lane >> 4;
  const int i0w = i0 + w * 4;
  const int i_lane = i0w + quad;

  // Q fragments (A-layout): m=col -> (query, g), k = quad*8 + dc*32
  short8 qf[4];
  {
    const int qi = i0w + (col >> 2);
    const int g = col & 3;
    const unsigned short* qp = qbf + (((size_t)qi * NHQ) + h * 4 + g) * DH + quad * 8;
#pragma unroll
    for (int dc = 0; dc < 4; ++dc) qf[dc] = *(const short8*)(qp + dc * 32);
  }
  const unsigned mymask = smask[(size_t)i_lane * NHKV + h];

  // block tile mask: OR of 16 query masks | window range (all causal)
  unsigned bmask;
  {
    unsigned mm = smask[(size_t)(i0 + col) * NHKV + h];
    mm |= __shfl_xor(mm, 1); mm |= __shfl_xor(mm, 2);
    mm |= __shfl_xor(mm, 4); mm |= __shfl_xor(mm, 8);
    const int whi = (i0 + 15) >> 6;
    int wl = i0 - WINW; wl = (wl < 0) ? 0 : (wl >> 6);
    const unsigned hibits = (whi >= 31) ? 0xffffffffu : ((1u << (whi + 1)) - 1u);
    bmask = mm | (hibits & ~((1u << wl) - 1u));
  }

  f32x4 accS[8], accW[8];
#pragma unroll
  for (int dt = 0; dt < 8; ++dt) { accS[dt] = f32x4{0.f,0.f,0.f,0.f}; accW[dt] = f32x4{0.f,0.f,0.f,0.f}; }
  float mS[4], mW[4], lS[4], lW[4];
#pragma unroll
  for (int r = 0; r < 4; ++r) { mS[r] = -INFINITY; mW[r] = -INFINITY; lS[r] = 0.f; lW[r] = 0.f; }

  // async staging (swizzled: chunk c stored at physical c ^ (row&7))
  auto stageK = [&](int b, int kb) {
#pragma unroll
    for (int qq = 0; qq < 4; ++qq) {
      const int q = w * 4 + qq;
      const int u = q * 64 + lane;
      const int r = u >> 4;
      const int c = (u & 15) ^ (r & 7);
      const unsigned short* g = kbf + ((size_t)((b * 64 + r) * NHKV + h)) * DH + c * 8;
      gload_lds16(g, &Ks[kb][q * 512]);
    }
  };
  auto stageV = [&](int b) {
#pragma unroll
    for (int qq = 0; qq < 4; ++qq) {
      const int q = w * 4 + qq;
      const int u = q * 64 + lane;
      const int r = u >> 3;
      const int c = (u & 7) ^ (r & 7);
      const unsigned short* g = vT + ((size_t)(h * DH + r)) * SEQ + b * 64 + c * 8;
      gload_lds16(g, &Vs[q * 512]);
    }
  };

  unsigned tmw = bmask;
  int cur = __builtin_ctz(tmw);   // bmask always nonzero (block 0 forced)
  tmw &= tmw - 1;
  int kb = 0;
  stageK(cur, 0);
  while (cur >= 0) {
    int nxt = -1;
    if (tmw) { nxt = __builtin_ctz(tmw); tmw &= tmw - 1; }
    __syncthreads();                 // K(cur) loads drained; Vs free
    stageV(cur);
    if (nxt >= 0) stageK(nxt, kb ^ 1);

    const int j0 = cur * 64;
    const bool wact = (j0 <= i0w + 3);
    const bool selbit = wact && ((mymask >> cur) & 1u);
    const bool selAny = (__ballot(selbit) != 0ull);
    const bool winAny = wact && (j0 + 63 >= i0w - WINW);

    f32x4 sc[4];
    auto softmax_p = [&](bool forsel, float* mrun, float* lrun, f32x4* acc) {
#pragma unroll
      for (int r = 0; r < 4; ++r) {
        float vv[4];
        float tmax = -INFINITY;
#pragma unroll
        for (int kt = 0; kt < 4; ++kt) {
          const int j = j0 + kt * 16 + col;
          const bool act = (j <= i_lane) && (forsel ? selbit : (j >= i_lane - WINW));
          vv[kt] = act ? sc[kt][r] * SCALE : -INFINITY;
          tmax = fmaxf(tmax, vv[kt]);
        }
        tmax = fmaxf(tmax, __shfl_xor(tmax, 1));
        tmax = fmaxf(tmax, __shfl_xor(tmax, 2));
        tmax = fmaxf(tmax, __shfl_xor(tmax, 4));
        tmax = fmaxf(tmax, __shfl_xor(tmax, 8));
        const float mn = fmaxf(mrun[r], tmax);
        const float a = (mn == -INFINITY) ? 1.f : __expf(mrun[r] - mn);
        float ls = 0.f;
        const int m = quad * 4 + r;
#pragma unroll
        for (int kt = 0; kt < 4; ++kt) {
          const float pp = (vv[kt] == -INFINITY) ? 0.f : __expf(vv[kt] - mn);
          ls += pp;
          const int n = kt * 16 + col;
          Ps[w][m * 64 + ((((n >> 3) ^ (m & 7))) << 3) + (n & 7)] = f2bf(pp);
        }
        lrun[r] = lrun[r] * a + ls;
        mrun[r] = mn;
#pragma unroll
        for (int dt = 0; dt < 8; ++dt) acc[dt][r] *= a;
      }
    };
    auto pv = [&](f32x4* acc) {
#pragma unroll
      for (int kt2 = 0; kt2 < 2; ++kt2) {
        short8 ap = *(const short8*)&Ps[w][col * 64 + ((((kt2 * 4 + quad) ^ (col & 7))) << 3)];
#pragma unroll
        for (int dt = 0; dt < 8; ++dt) {
          const int rv = dt * 16 + col;
          short8 vfr = *(const short8*)&Vs[rv * 64 + ((((kt2 * 4 + quad) ^ (rv & 7))) << 3)];
          acc[dt] = __builtin_amdgcn_mfma_f32_16x16x32_bf16(ap, vfr, acc[dt], 0, 0, 0);
        }
      }
    };

    if (selAny || winAny) {
      // phase 1: QK scores + sel softmax/P-write (overlaps V staging)
#pragma unroll
      for (int kt = 0; kt < 4; ++kt) {
        f32x4 ss = f32x4{0.f, 0.f, 0.f, 0.f};
        const int row = kt * 16 + col;
#pragma unroll
        for (int dc = 0; dc < 4; ++dc) {
          short8 kf = *(const short8*)&Ks[kb][row * 128 + ((((dc * 4 + quad) ^ (col & 7))) << 3)];
          ss = __builtin_amdgcn_mfma_f32_16x16x32_bf16(qf[dc], kf, ss, 0, 0, 0);
        }
        sc[kt] = ss;
      }
      if (selAny) softmax_p(true, mS, lS, accS);
    }
    __syncthreads();                 // V(cur) loads drained
    if (selAny) pv(accS);
    if (winAny) { softmax_p(false, mW, lW, accW); pv(accW); }

    cur = nxt;
    kb ^= 1;
  }

  // epilogue
#pragma unroll
  for (int r = 0; r < 4; ++r) {
    float v = lS[r];
    v += __shfl_xor(v, 1); v += __shfl_xor(v, 2); v += __shfl_xor(v, 4); v += __shfl_xor(v, 8);
    lS[r] = v;
    float u = lW[r];
    u += __shfl_xor(u, 1); u += __shfl_xor(u, 2); u += __shfl_xor(u, 4); u += __shfl_xor(u, 8);
    lW[r] = u;
  }
  const float g0 = gate[i_lane * 3 + 0];
  const float g1 = gate[i_lane * 3 + 1];
  const float g2 = gate[i_lane * 3 + 2];
#pragma unroll
  for (int r = 0; r < 4; ++r) {
    const size_t base = ((size_t)i_lane * NHQ + h * 4 + r) * DH;
    const float rls = g1 / lS[r];
    const float rlw = g2 / lW[r];
#pragma unroll
    for (int dt = 0; dt < 8; ++dt) {
      const size_t o = base + dt * 16 + col;
      outc[o] = f2bf(g0 * bf2f(cmpo[o]) + rls * accS[dt][r] + rlw * accW[dt][r]);
    }
  }
}

// ---------------- launcher ----------------
extern "C" void kernel_launch(void* const* d_in, const int* in_sizes, int n_in,
                              void* d_out, int out_size, void* d_ws, size_t ws_size,
                              hipStream_t stream) {
  const float* x   = (const float*)d_in[0];
  const float* Wq  = (const float*)d_in[2];
  const float* Wk  = (const float*)d_in[3];
  const float* Wv  = (const float*)d_in[4];
  const float* Wo  = (const float*)d_in[5];
  const float* Wck = (const float*)d_in[6];
  const float* Wcv = (const float*)d_in[7];
  const float* pe  = (const float*)d_in[8];
  const float* Wg  = (const float*)d_in[9];
  float* out = (float*)d_out;

  unsigned char* p = (unsigned char*)d_ws;
  auto alloc = [&](size_t bytes) { void* r = p; p += (bytes + 255) & ~(size_t)255; return r; };
  float* qkv  = (float*)alloc((size_t)SEQ * NQKV * 4);        // 24MB; later hosts WoT (0-8M) + combbf (8-16M)
  float* gbuf = (float*)alloc((size_t)SEQ * 4 * 4);
  unsigned* smask = (unsigned*)alloc((size_t)SEQ * NHKV * 4);
  unsigned short* ckbf = (unsigned short*)alloc((size_t)128 * NHKV * DH * 2);
  unsigned short* cvbf = (unsigned short*)alloc((size_t)128 * NHKV * DH * 2);
  unsigned short* xbf  = (unsigned short*)alloc((size_t)SEQ * HID * 2);        // 8MB; -> Ak/Av -> cmpobf
  unsigned short* WqkvT = (unsigned short*)alloc((size_t)NQKV * HID * 2);      // 12MB; -> qbf/krbf/vT
  unsigned short* WckT = (unsigned short*)alloc((size_t)NHKV * DH * CKD * 2);  // 4MB
  unsigned short* WcvT = (unsigned short*)alloc((size_t)NHKV * DH * CKD * 2);  // 4MB
  float* Cpart = (float*)alloc((size_t)32 * 128 * 128 * 4);                    // 2MB
  unsigned short* WoT    = (unsigned short*)qkv;                                // 8MB
  unsigned short* combbf = (unsigned short*)qkv + (size_t)NHQ * DH * HID;       // next 8MB
  unsigned short* Ak     = xbf;
  unsigned short* Av     = xbf + (size_t)NHKV * 128 * CKD;
  unsigned short* cmpobf = xbf;
  unsigned short* qbf  = WqkvT;                                  // 8MB
  unsigned short* krbf = WqkvT + (size_t)HID * HID;              // 2MB
  unsigned short* vT   = WqkvT + (size_t)(HID + NHKV * DH) * HID;// 2MB

  // convert / transpose weights + x
  conv_bf_kernel<<<(SEQ * HID) / 256, 256, 0, stream>>>(x, xbf);
  transpose_bf_kernel<<<dim3(HID / 32, HID / 32), dim3(32, 8), 0, stream>>>(Wq, WqkvT, HID, HID);
  transpose_bf_kernel<<<dim3((NHKV * DH) / 32, HID / 32), dim3(32, 8), 0, stream>>>(Wk, WqkvT + (size_t)HID * HID, HID, NHKV * DH);
  transpose_bf_kernel<<<dim3((NHKV * DH) / 32, HID / 32), dim3(32, 8), 0, stream>>>(Wv, WqkvT + (size_t)(HID + NHKV * DH) * HID, HID, NHKV * DH);
  transpose_bf_kernel<<<dim3(DH / 32, CKD / 32, NHKV), dim3(32, 8), 0, stream>>>(Wck, WckT, CKD, DH);
  transpose_bf_kernel<<<dim3(DH / 32, CKD / 32, NHKV), dim3(32, 8), 0, stream>>>(Wcv, WcvT, CKD, DH);
  // fused q/k/v projection
  gemm_bf16_128<<<dim3(NQKV / 128, SEQ / 128), 256, 0, stream>>>(xbf, WqkvT, qkv, SEQ, NQKV, HID);
  gate_kernel<<<SEQ, 128, 0, stream>>>(x, Wg, gbuf);
  // compression as GEMM
  abuild_kernel<<<(NHKV * 128 * CKD) / 256, 256, 0, stream>>>(qkv, pe, Ak, Av);
  compress_gemm<<<32, 256, 0, stream>>>(Ak, Av, WckT, WcvT, Cpart);
  compress_reduce_rope<<<(32768 + 65536) / 256, 256, 0, stream>>>(Cpart, ckbf, cvbf);
  // RoPE + V transpose (overwrite WqkvT after projection)
  rope_q_kernel<<<SEQ * NHQ, 64, 0, stream>>>(qkv, qbf);
  rope_k_kernel<<<SEQ * NHKV, 64, 0, stream>>>(qkv, krbf);
  vtrans_kernel<<<dim3(SEQ / 32, DH / 32, NHKV), dim3(32, 8), 0, stream>>>(qkv, vT);
  // Wo transpose into dead qkv region (after all qkv consumers)
  transpose_bf_kernel<<<dim3(HID / 32, (NHQ * DH) / 32), dim3(32, 8), 0, stream>>>(Wo, WoT, NHQ * DH, HID);
  // compressed attention + selection
  cmp_attn_mfma<<<(SEQ / 16) * NHKV, 256, 0, stream>>>(qbf, ckbf, cvbf, cmpobf, smask);
  // selected + window attention + gated combine
  nsa_attn_kernel<<<(SEQ / 16) * NHKV, 256, 0, stream>>>(qbf, krbf, vT, smask, gbuf, cmpobf, combbf);
  // output projection
  gemm_bf16_128<<<dim3(HID / 128, SEQ / 128), 256, 0, stream>>>(combbf, WoT, out, SEQ, HID, NHQ * DH);
}